// Round 5
// baseline (1265.169 us; speedup 1.0000x reference)
//
#include <hip/hip_runtime.h>

typedef unsigned short us;
typedef unsigned int u32;
typedef unsigned long long u64;
typedef __bf16 bf16x8 __attribute__((ext_vector_type(8)));
typedef float f32x4 __attribute__((ext_vector_type(4)));

#define MFMA(a,b,c) __builtin_amdgcn_mfma_f32_16x16x32_bf16(a,b,c,0,0,0)

__device__ __forceinline__ us f2bf(float f){
  u32 u = __builtin_bit_cast(u32, f);
  u += 0x7fffu + ((u>>16)&1u);
  return (us)(u>>16);
}
__device__ __forceinline__ float bf2f(us h){
  u32 u = ((u32)h)<<16;
  return __builtin_bit_cast(float, u);
}
__device__ __forceinline__ float sigf(float x){ return 1.0f/(1.0f+__expf(-x)); }
__device__ __forceinline__ float tanh_(float x){ float e=__expf(2.0f*x); return 1.0f - 2.0f/(e+1.0f); }

// ---------------- prep kernels ----------------

// Wc permuted to MFMA-fragment-linear order per 16-e slice:
// dst us index: (((eb*24 + kc)*4 + g)*64 + qd*16 + ln)*8 + i
__global__ void k_prep_wperm(const float* __restrict__ w_hh, const float* __restrict__ w_ih,
                             const float* __restrict__ b_ih, const float* __restrict__ b_hh,
                             us* __restrict__ Wp, float* __restrict__ biasc){
  int n = blockIdx.x; int c = threadIdx.x;          // n<2048, c<768
  float v = (c < 512) ? w_hh[(size_t)n*512 + c] : w_ih[(size_t)n*256 + (c-512)];
  int g = n >> 9, eg = n & 511, eb = eg >> 4, ln = eg & 15;
  int kc = c >> 5, qd = (c >> 3) & 3, i = c & 7;
  size_t dst = ((((size_t)eb*24 + kc)*4 + g)*64 + (size_t)(qd*16 + ln))*8 + i;
  Wp[dst] = f2bf(v);
  if (c == 0) biasc[n] = b_ih[n] + b_hh[n];
}

__global__ void k_prep_state(const float* __restrict__ ch, const float* __restrict__ th,
                             const float* __restrict__ cc, const float* __restrict__ tc,
                             us* __restrict__ h0, float* __restrict__ c0){
  int i = blockIdx.x*256 + threadIdx.x;   // 262144
  int b = i>>9, e = i&511;
  float hv = (e<256)? ch[b*256+e] : th[b*256+e-256];
  float cv = (e<256)? cc[b*256+e] : tc[b*256+e-256];
  h0[i] = f2bf(hv); c0[i] = cv;
}

// xbf[t][b][v] = bf16(true_output[b][t][v])
__global__ void k_xprep(const float* __restrict__ x, us* __restrict__ xbf){
  int g = blockIdx.x*256 + threadIdx.x;      // 1,048,576 groups of 8 elements
  int v0 = (g & 31) * 8;
  int b  = (g >> 5) & 511;
  int t  = g >> 14;
  const float4* src = (const float4*)(x + ((size_t)(b*64 + t))*256 + v0);
  float4 f0 = src[0], f1 = src[1];
  uint4 pk;
  pk.x = (u32)f2bf(f0.x) | ((u32)f2bf(f0.y)<<16);
  pk.y = (u32)f2bf(f0.z) | ((u32)f2bf(f0.w)<<16);
  pk.z = (u32)f2bf(f1.x) | ((u32)f2bf(f1.y)<<16);
  pk.w = (u32)f2bf(f1.z) | ((u32)f2bf(f1.w)<<16);
  *(uint4*)(xbf + ((size_t)t*512 + b)*256 + v0) = pk;
}

// u[j] = sum_e bq[e]*wk[e][j]
__global__ void k_uvec(const float* __restrict__ bq, const float* __restrict__ wk,
                       float* __restrict__ u){
  int j = blockIdx.x*128 + threadIdx.x;
  float a = 0.f;
  for (int e=0;e<512;++e) a += bq[e]*wk[(size_t)e*512 + j];
  u[j] = a;
}

// p[i] = sum_j wo[i][j]*bv[j] + bo[i]
__global__ void k_pvec(const float* __restrict__ wo, const float* __restrict__ bv,
                       const float* __restrict__ bo, float* __restrict__ p){
  int i = blockIdx.x*128 + threadIdx.x;
  float a = bo[i];
  for (int j=0;j<512;++j) a += wo[(size_t)i*512+j]*bv[j];
  p[i] = a;
}

// bc[v] = out_b[v] + out_w[v,:512]@pc + out_w[v,512:]@pt
__global__ void k_bc(const float* __restrict__ out_w, const float* __restrict__ pc,
                     const float* __restrict__ pt, const float* __restrict__ out_b,
                     float* __restrict__ bc){
  int v = threadIdx.x;
  float a = out_b[v];
  for (int i=0;i<512;++i) a += out_w[(size_t)v*1024+i]*pc[i];
  for (int i=0;i<512;++i) a += out_w[(size_t)v*1024+512+i]*pt[i];
  bc[v] = a;
}

// ---- small MFMA prep GEMM ----
template<bool TA, int OMODE>
__global__ __launch_bounds__(256) void k_pgemm(const float* __restrict__ A, int lda,
    const float* __restrict__ B, int ldb, void* C1, void* C2, int ldc, int K){
  __shared__ us As[64][40];
  __shared__ us Bs[64][40];
  int tid=threadIdx.x, w=tid>>6, lane=tid&63, qd=lane>>4, ln=lane&15;
  int m0 = blockIdx.x*64, n0 = blockIdx.y*64;
  f32x4 acc[4] = {};
  for (int kc=0; kc<K/32; ++kc){
    int k0 = kc*32;
    if (!TA){
      int r=tid>>2, c=(tid&3)*8;
      const float* ap = A + (size_t)(m0+r)*lda + k0 + c;
      float4 f0=*(const float4*)ap, f1=*(const float4*)(ap+4);
      uint4 pk;
      pk.x=(u32)f2bf(f0.x)|((u32)f2bf(f0.y)<<16);
      pk.y=(u32)f2bf(f0.z)|((u32)f2bf(f0.w)<<16);
      pk.z=(u32)f2bf(f1.x)|((u32)f2bf(f1.y)<<16);
      pk.w=(u32)f2bf(f1.z)|((u32)f2bf(f1.w)<<16);
      *(uint4*)&As[r][c] = pk;
    } else {
      int kk=tid>>3, mp=(tid&7)*8;
      const float* ap = A + (size_t)(k0+kk)*lda + m0 + mp;
      #pragma unroll
      for (int i=0;i<8;++i) As[mp+i][kk] = f2bf(ap[i]);
    }
    { int kk=tid>>3, np=(tid&7)*8;
      const float* bp = B + (size_t)(k0+kk)*ldb + n0 + np;
      #pragma unroll
      for (int i=0;i<8;++i) Bs[np+i][kk] = f2bf(bp[i]);
    }
    __syncthreads();
    bf16x8 a = *(const bf16x8*)&As[16*w+ln][qd*8];
    #pragma unroll
    for (int j=0;j<4;++j){
      bf16x8 bb = *(const bf16x8*)&Bs[16*j+ln][qd*8];
      acc[j] = MFMA(a, bb, acc[j]);
    }
    __syncthreads();
  }
  #pragma unroll
  for (int j=0;j<4;++j){
    #pragma unroll
    for (int r=0;r<4;++r){
      size_t idx = (size_t)(m0+16*w+qd*4+r)*ldc + (n0+16*j+ln);
      float v = acc[j][r];
      if (OMODE==0) ((float*)C1)[idx] = v;
      else if (OMODE==1) ((us*)C1)[idx] = f2bf(v);
      else {
        us h = f2bf(v);
        ((us*)C1)[idx] = h;
        ((us*)C2)[idx] = f2bf(v - bf2f(h));
      }
    }
  }
}

// ---------------- persistent LSTM v3 (2 blocks/CU) ----------------
// 512 blocks = 32 e-slices (eb) x 16 b-groups (bb, 32 rows each), 256 threads.
// LDS = W_hh slice (64KB, kc 0..15) + 8KB exchange -> 72KB -> 2 blocks/CU
// (8 waves/CU = 2/SIMD for latency hiding). x-part W fragments read directly
// from global (L1/L2-hot). Wave pair (p, hf): hf splits h-kc 8/8; partial
// acc[4] exchanged via swizzled LDS; cell update split 2 rows per wave.
// x-part (4 x-kc per wave) MFMA'd during the barrier wait.
// h exchange: relaxed agent-scope 8B atomic stores/loads (fence-free, r4).
__global__ __launch_bounds__(256, 2) void k_lstm_all2(
    const us* __restrict__ h0, const us* __restrict__ xbf,
    const us* __restrict__ Wp, const float* __restrict__ biasc,
    const float* __restrict__ c0, us* __restrict__ hs,
    unsigned* __restrict__ bars){
  extern __shared__ us smem[];           // 65536B Wf + 8192B exch = 73728B
  us*    Wf   = smem;                    // [16 kc][4 g][64 lane][8]
  float* exch = (float*)(smem + 32768);  // byte offset 65536; [4 wave][512 f]
  int tid = threadIdx.x, w = tid>>6, lane = tid&63, qd = lane>>4, ln = lane&15;
  int hf = w & 1, p = w >> 1;
  int bb = blockIdx.x & 15, eb = blockIdx.x >> 4;
  int b0 = bb*32, e0 = eb*16;
  // load h-part W slice (first 65536B of this eb's 98304B Wp slice)
  {
    const uint4* src = (const uint4*)(Wp + (size_t)eb*49152);
    uint4* dst = (uint4*)Wf;
    #pragma unroll
    for (int i=0;i<16;++i) dst[tid + 256*i] = src[tid + 256*i];
  }
  int bA = b0 + 16*p + ln;              // A-fragment row
  int bC = b0 + 16*p + qd*4 + hf*2;     // first owned cell row (+r, r<2)
  int e  = e0 + ln;
  float bias_[4];
  #pragma unroll
  for (int j=0;j<4;++j) bias_[j] = biasc[j*512 + e];
  float c_[2];
  #pragma unroll
  for (int r=0;r<2;++r) c_[r] = c0[(size_t)(bC+r)*512 + e];
  __syncthreads();
  unsigned* bar = bars + bb*64;          // 256B apart per group
  f32x4 xa[4] = {};                      // x-part partial for current step (x_0=0)
  const int kh0 = hf*8;                  // this wave's h-kc base
  for (int t=0; t<64; ++t){
    if (t > 0){
      unsigned tgt = 32u*(unsigned)t;
      while (__hip_atomic_load(bar, __ATOMIC_RELAXED, __HIP_MEMORY_SCOPE_AGENT) < tgt)
        __builtin_amdgcn_s_sleep(2);
      // no fence: h loads below are agent-scope atomic (coherence-point) loads
    }
    bf16x8 afr[8];
    if (t == 0){
      const us* hrow = h0 + (size_t)bA*512;
      #pragma unroll
      for (int k=0;k<8;++k)
        afr[k] = *(const bf16x8*)(hrow + (kh0+k)*32 + qd*8);
    } else {
      const u64* hq = (const u64*)(hs + ((size_t)bA*64 + (t-1))*512);
      u64 q0[8], q1[8];
      #pragma unroll
      for (int k=0;k<8;++k){
        q0[k] = __hip_atomic_load(hq + (kh0+k)*8 + qd*2 + 0, __ATOMIC_RELAXED, __HIP_MEMORY_SCOPE_AGENT);
        q1[k] = __hip_atomic_load(hq + (kh0+k)*8 + qd*2 + 1, __ATOMIC_RELAXED, __HIP_MEMORY_SCOPE_AGENT);
      }
      #pragma unroll
      for (int k=0;k<8;++k){
        union { u64 q[2]; bf16x8 v; } u_;
        u_.q[0] = q0[k]; u_.q[1] = q1[k];
        afr[k] = u_.v;
      }
    }
    f32x4 acc[4] = {xa[0], xa[1], xa[2], xa[3]};
    #pragma unroll
    for (int k=0;k<8;++k){
      int kc = kh0 + k;
      #pragma unroll
      for (int j=0;j<4;++j){
        bf16x8 bfrag = *(const bf16x8*)&Wf[(size_t)((kc*4+j)*64 + lane)*8];
        acc[j] = MFMA(afr[k], bfrag, acc[j]);
      }
    }
    // ---- pair exchange: write non-owned r-pair, add partner's partial ----
    {
      int rw = (hf^1)*2;   // rows I write = partner's owned pair
      #pragma unroll
      for (int k=0;k<2;++k){
        int c = lane*2 + k;
        int cs = c ^ ((c>>3)&7);       // bank swizzle (bijective per 8-chunk)
        float4 v = { acc[2*k+0][rw], acc[2*k+0][rw+1],
                     acc[2*k+1][rw], acc[2*k+1][rw+1] };
        *(float4*)(exch + (size_t)w*512 + cs*4) = v;
      }
      __syncthreads();
      #pragma unroll
      for (int k=0;k<2;++k){
        int c = lane*2 + k;
        int cs = c ^ ((c>>3)&7);
        float4 v = *(const float4*)(exch + (size_t)(w^1)*512 + cs*4);
        acc[2*k+0][hf*2+0] += v.x;
        acc[2*k+0][hf*2+1] += v.y;
        acc[2*k+1][hf*2+0] += v.z;
        acc[2*k+1][hf*2+1] += v.w;
      }
    }
    // ---- cell update for owned rows bC+0, bC+1 ----
    us hb[2];
    #pragma unroll
    for (int r=0;r<2;++r){
      float iv = acc[0][hf*2+r]+bias_[0], fv = acc[1][hf*2+r]+bias_[1];
      float gv = acc[2][hf*2+r]+bias_[2], ov = acc[3][hf*2+r]+bias_[3];
      float cc2 = sigf(fv)*c_[r] + sigf(iv)*tanh_(gv);
      c_[r] = cc2;
      hb[r] = f2bf(sigf(ov)*tanh_(cc2));
    }
    // pack 4 lanes' bf16 into 8B, write-through agent-scope store
    #pragma unroll
    for (int r=0;r<2;++r){
      u32 v = hb[r];
      u32 pk = v | (((u32)__shfl_xor((int)v, 1)) << 16);
      u64 q = (u64)pk | (((u64)(u32)__shfl_xor((int)pk, 2)) << 32);
      if ((lane & 3) == 0){
        size_t idx = ((size_t)(bC+r)*64 + t)*512 + e0 + ln;   // ln multiple of 4
        __hip_atomic_store((u64*)(hs + idx), q, __ATOMIC_RELAXED, __HIP_MEMORY_SCOPE_AGENT);
      }
    }
    if (t < 63){
      __syncthreads();   // drains vmcnt(0): h stores at L3 before the add
      if (tid == 0)
        __hip_atomic_fetch_add(bar, 1u, __ATOMIC_RELAXED, __HIP_MEMORY_SCOPE_AGENT);
      // overlap: x-part for t+1 (this wave's 4 x-kc; W frags from global)
      const us* xrow = xbf + ((size_t)(t+1)*512 + bA)*256;
      f32x4 xn[4] = {};
      #pragma unroll
      for (int k=0;k<4;++k){
        int kx = hf*4 + k;
        bf16x8 xf = *(const bf16x8*)(xrow + kx*32 + qd*8);
        #pragma unroll
        for (int j=0;j<4;++j){
          bf16x8 bw = *(const bf16x8*)(Wp + ((size_t)(eb*24 + 16 + kx)*4 + j)*512 + lane*8);
          xn[j] = MFMA(xf, bw, xn[j]);
        }
      }
      #pragma unroll
      for (int j=0;j<4;++j) xa[j] = xn[j];
    }
  }
}

// ------- C = bf16(alpha*(A @ W^T + bias)), A bf16 (M x 512), W bf16 (N x 512) -------
__global__ __launch_bounds__(256) void k_gemm(
    const us* __restrict__ Ap, const us* __restrict__ W,
    const float* __restrict__ bias, float alpha, us* __restrict__ C){
  __shared__ us As[128][40];
  __shared__ us Ws[128][40];
  int tid = threadIdx.x; int w = tid>>6; int lane=tid&63;
  int qd=lane>>4, ln=lane&15;
  int m0 = blockIdx.x*128, n0 = blockIdx.y*128;
  int wm = (w&1)*64, wn=(w>>1)*64;
  f32x4 acc[4][4] = {};
  int row = tid>>1; int cp = (tid&1)*16;
  for (int kc=0;kc<16;++kc){
    int k0=kc*32;
    { const uint4* ap = (const uint4*)(Ap + (size_t)(m0+row)*512 + k0+cp);
      *(uint4*)&As[row][cp]=ap[0]; *(uint4*)&As[row][cp+8]=ap[1];
    }
    { const uint4* wp = (const uint4*)(W + (size_t)(n0+row)*512 + k0+cp);
      *(uint4*)&Ws[row][cp]=wp[0]; *(uint4*)&Ws[row][cp+8]=wp[1];
    }
    __syncthreads();
    bf16x8 af[4], bfr[4];
    #pragma unroll
    for (int i=0;i<4;++i) af[i]  = *(const bf16x8*)&As[wm+16*i+ln][qd*8];
    #pragma unroll
    for (int j=0;j<4;++j) bfr[j] = *(const bf16x8*)&Ws[wn+16*j+ln][qd*8];
    #pragma unroll
    for (int i=0;i<4;++i)
      #pragma unroll
      for (int j=0;j<4;++j) acc[i][j]=MFMA(af[i],bfr[j],acc[i][j]);
    __syncthreads();
  }
  #pragma unroll
  for (int j=0;j<4;++j){
    int col = n0+wn+16*j+ln;
    float bv = bias[col];
    #pragma unroll
    for (int i=0;i<4;++i){
      #pragma unroll
      for (int r=0;r<4;++r){
        int rm = m0+wm+16*i+qd*4+r;
        C[(size_t)rm*512 + col] = f2bf(alpha*(acc[i][j][r]+bv));
      }
    }
  }
}

// ---------------- fused attention + output projection (v3) ----------------
template<int S>
struct alignas(16) ASmem3 {
  static constexpr int SP  = (S<32)?32:S;
  static constexpr int SPp = SP+8;
  us Pbh[64][SPp];
  us Pbl[64][SPp];
  union {
    us Es[S][72];
    struct { us Eh[64][72]; us El[64][72]; } t;
  } u;
  us Ph[64][72];
  us Pl[64][72];
};

template<int S, bool ACC>
__global__ __launch_bounds__(256) void k_attn3(const us* __restrict__ hGp,
    const float* __restrict__ enc, const us* __restrict__ Mvh,
    const us* __restrict__ Mvl, float* __restrict__ out){
  constexpr int NJ  = S/16;
  constexpr int KC2 = ((S<32)?32:S)/32;
  extern __shared__ char smraw[];
  ASmem3<S>& sm = *reinterpret_cast<ASmem3<S>*>(smraw);
  int b = blockIdx.x;
  int tid=threadIdx.x, w=tid>>6, lane=tid&63, qd=lane>>4, ln=lane&15;

  // ---- phase 1: S = hG @ enc^T ----
  f32x4 sacc[NJ];
  #pragma unroll
  for (int j=0;j<NJ;++j) sacc[j] = (f32x4){0.f,0.f,0.f,0.f};
  const us* hrow = hGp + ((size_t)(b*64 + 16*w + ln))*512;
  for (int ec=0; ec<8; ++ec){
    int e0 = ec*64;
    { int s = tid>>2, ep=(tid&3)*16;
      if (S==64 || tid < 4*S){
        const float* ap = enc + ((size_t)b*S + s)*512 + e0 + ep;
        float4 f0=*(const float4*)ap, f1=*(const float4*)(ap+4);
        float4 f2=*(const float4*)(ap+8), f3=*(const float4*)(ap+12);
        float fv[16]={f0.x,f0.y,f0.z,f0.w,f1.x,f1.y,f1.z,f1.w,
                      f2.x,f2.y,f2.z,f2.w,f3.x,f3.y,f3.z,f3.w};
        u32 pk[8];
        #pragma unroll
        for (int i=0;i<8;++i)
          pk[i] = (u32)f2bf(fv[2*i]) | ((u32)f2bf(fv[2*i+1])<<16);
        uint4* d = (uint4*)&sm.u.Es[s][ep];
        d[0] = make_uint4(pk[0],pk[1],pk[2],pk[3]);
        d[1] = make_uint4(pk[4],pk[5],pk[6],pk[7]);
      }
    }
    __syncthreads();
    #pragma unroll
    for (int kcl=0;kcl<2;++kcl){
      bf16x8 a = *(const bf16x8*)(hrow + e0 + kcl*32 + qd*8);
      #pragma unroll
      for (int j=0;j<NJ;++j){
        bf16x8 bb = *(const bf16x8*)&sm.u.Es[16*j+ln][kcl*32+qd*8];
        sacc[j] = MFMA(a, bb, sacc[j]);
      }
    }
    __syncthreads();
  }

  // ---- softmax, fully in-register ----
  #pragma unroll
  for (int r=0;r<4;++r){
    float m = sacc[0][r];
    #pragma unroll
    for (int j=1;j<NJ;++j) m = fmaxf(m, sacc[j][r]);
    #pragma unroll
    for (int dl=1; dl<16; dl<<=1) m = fmaxf(m, __shfl_xor(m, dl));
    float ssum = 0.f;
    #pragma unroll
    for (int j=0;j<NJ;++j){ float e_=__expf(sacc[j][r]-m); sacc[j][r]=e_; ssum+=e_; }
    #pragma unroll
    for (int dl=1; dl<16; dl<<=1) ssum += __shfl_xor(ssum, dl);
    float inv = 1.0f/ssum;
    int R = 16*w + qd*4 + r;
    #pragma unroll
    for (int j=0;j<NJ;++j){
      float pv = sacc[j][r]*inv;
      us h = f2bf(pv);
      sm.Pbh[R][16*j+ln] = h;
      sm.Pbl[R][16*j+ln] = f2bf(pv - bf2f(h));
    }
    if (S==16){ sm.Pbh[R][16+ln]=0; sm.Pbl[R][16+ln]=0; }
  }

  // ---- phase 2 ----
  f32x4 Lacc[4][4] = {};
  for (int ec=0; ec<8; ++ec){
    int e0 = ec*64;
    { int s = tid>>2, ep=(tid&3)*16;
      if (S==64 || tid < 4*S){
        const float* ap = enc + ((size_t)b*S + s)*512 + e0 + ep;
        float4 f0=*(const float4*)ap, f1=*(const float4*)(ap+4);
        float4 f2=*(const float4*)(ap+8), f3=*(const float4*)(ap+12);
        float fv[16]={f0.x,f0.y,f0.z,f0.w,f1.x,f1.y,f1.z,f1.w,
                      f2.x,f2.y,f2.z,f2.w,f3.x,f3.y,f3.z,f3.w};
        #pragma unroll
        for (int i=0;i<16;++i){
          float v = fv[i]; us h = f2bf(v);
          sm.u.t.Eh[ep+i][s] = h;
          sm.u.t.El[ep+i][s] = f2bf(v - bf2f(h));
        }
      } else if (S==16 && tid < 128){
        int s2 = 16 + ((tid-64)>>2);
        #pragma unroll
        for (int i=0;i<16;++i){ sm.u.t.Eh[ep+i][s2]=0; sm.u.t.El[ep+i][s2]=0; }
      }
    }
    __syncthreads();
    f32x4 pacc[4] = {};
    #pragma unroll
    for (int kcl=0;kcl<KC2;++kcl){
      bf16x8 ah = *(const bf16x8*)&sm.Pbh[16*w+ln][kcl*32+qd*8];
      bf16x8 al = *(const bf16x8*)&sm.Pbl[16*w+ln][kcl*32+qd*8];
      #pragma unroll
      for (int j=0;j<4;++j){
        bf16x8 bh = *(const bf16x8*)&sm.u.t.Eh[16*j+ln][kcl*32+qd*8];
        bf16x8 bl = *(const bf16x8*)&sm.u.t.El[16*j+ln][kcl*32+qd*8];
        pacc[j] = MFMA(ah, bh, pacc[j]);
        pacc[j] = MFMA(ah, bl, pacc[j]);
        pacc[j] = MFMA(al, bh, pacc[j]);
      }
    }
    #pragma unroll
    for (int j=0;j<4;++j)
      #pragma unroll
      for (int r=0;r<4;++r){
        float v = pacc[j][r]; us h = f2bf(v);
        sm.Ph[16*w+qd*4+r][16*j+ln] = h;
        sm.Pl[16*w+qd*4+r][16*j+ln] = f2bf(v - bf2f(h));
      }
    __syncthreads();
    #pragma unroll
    for (int kcl=0;kcl<2;++kcl){
      bf16x8 ah[4], al[4];
      #pragma unroll
      for (int i=0;i<4;++i){
        ah[i] = *(const bf16x8*)&sm.Ph[16*i+ln][kcl*32+qd*8];
        al[i] = *(const bf16x8*)&sm.Pl[16*i+ln][kcl*32+qd*8];
      }
      #pragma unroll
      for (int j=0;j<4;++j){
        int v = 64*w + 16*j + ln;
        bf16x8 mh = *(const bf16x8*)(Mvh + (size_t)v*512 + e0 + kcl*32 + qd*8);
        bf16x8 ml = *(const bf16x8*)(Mvl + (size_t)v*512 + e0 + kcl*32 + qd*8);
        #pragma unroll
        for (int i=0;i<4;++i){
          Lacc[i][j] = MFMA(ah[i], mh, Lacc[i][j]);
          Lacc[i][j] = MFMA(ah[i], ml, Lacc[i][j]);
          Lacc[i][j] = MFMA(al[i], mh, Lacc[i][j]);
        }
      }
    }
  }
  // epilogue
  #pragma unroll
  for (int i=0;i<4;++i){
    #pragma unroll
    for (int j=0;j<4;++j){
      int v = 64*w + 16*j + ln;
      #pragma unroll
      for (int r=0;r<4;++r){
        size_t addr = ((size_t)b*64 + 16*i + qd*4 + r)*256 + v;
        if (ACC) out[addr] += Lacc[i][j][r];
        else     out[addr]  = Lacc[i][j][r];
      }
    }
  }
}

// ---------------- entmax-1.5 in place over rows of 256 ----------------
__global__ __launch_bounds__(256) void k_entmax(float* __restrict__ out,
                                                const float* __restrict__ bc){
  int tid=threadIdx.x; int w=tid>>6; int lane=tid&63;
  float4 bcv = *(const float4*)(bc + lane*4);
  int base = blockIdx.x*16 + w*4;
  for (int i=0;i<4;++i){
    int row = base + i;
    float* rp = out + (size_t)row*256 + lane*4;
    float4 d = *(const float4*)rp;
    float z[4] = {0.5f*(d.x+bcv.x), 0.5f*(d.y+bcv.y), 0.5f*(d.z+bcv.z), 0.5f*(d.w+bcv.w)};
    float m = fmaxf(fmaxf(z[0],z[1]), fmaxf(z[2],z[3]));
    #pragma unroll
    for (int dl=1; dl<64; dl<<=1) m = fmaxf(m, __shfl_xor(m, dl));
    #pragma unroll
    for (int k=0;k<4;++k) z[k] -= m;
    float tau = -1.0f;
    for (int it=0; it<14; ++it){
      float s1=0.f, s2=0.f;
      #pragma unroll
      for (int k=0;k<4;++k){
        float dd = z[k]-tau; dd = fmaxf(dd, 0.f);
        s1 += dd; s2 += dd*dd;
      }
      #pragma unroll
      for (int dl=1; dl<64; dl<<=1){ s1 += __shfl_xor(s1, dl); s2 += __shfl_xor(s2, dl); }
      tau += (s2 - 1.0f) / (2.0f*fmaxf(s1, 1e-12f));
    }
    float4 y;
    { float dd;
      dd = fmaxf(z[0]-tau,0.f); y.x = dd*dd;
      dd = fmaxf(z[1]-tau,0.f); y.y = dd*dd;
      dd = fmaxf(z[2]-tau,0.f); y.z = dd*dd;
      dd = fmaxf(z[3]-tau,0.f); y.w = dd*dd;
    }
    *(float4*)rp = y;
  }
}

// ---------------- launch ----------------

extern "C" void kernel_launch(void* const* d_in, const int* in_sizes, int n_in,
                              void* d_out, int out_size, void* d_ws, size_t ws_size,
                              hipStream_t stream){
  (void)in_sizes; (void)n_in; (void)out_size; (void)ws_size;
  const float* char_enc = (const float*)d_in[0];
  const float* char_hn0 = (const float*)d_in[1];
  const float* char_cn0 = (const float*)d_in[2];
  const float* tag_enc  = (const float*)d_in[3];
  const float* tag_hn0  = (const float*)d_in[4];
  const float* tag_cn0  = (const float*)d_in[5];
  const float* true_out = (const float*)d_in[6];
  const float* w_ih = (const float*)d_in[7];
  const float* w_hh = (const float*)d_in[8];
  const float* b_ih = (const float*)d_in[9];
  const float* b_hh = (const float*)d_in[10];
  const float* c_wq = (const float*)d_in[11];
  const float* c_wk = (const float*)d_in[12];
  const float* c_wv = (const float*)d_in[13];
  const float* c_bq = (const float*)d_in[14];
  const float* c_bv = (const float*)d_in[16];
  const float* c_wo = (const float*)d_in[17];
  const float* c_bo = (const float*)d_in[18];
  const float* t_wq = (const float*)d_in[19];
  const float* t_wk = (const float*)d_in[20];
  const float* t_wv = (const float*)d_in[21];
  const float* t_bq = (const float*)d_in[22];
  const float* t_bv = (const float*)d_in[24];
  const float* t_wo = (const float*)d_in[25];
  const float* t_bo = (const float*)d_in[26];
  const float* out_w = (const float*)d_in[27];
  const float* out_b = (const float*)d_in[28];
  float* out = (float*)d_out;

  char* base = (char*)d_ws;
  // region A: prep/LSTM scratch, later overwritten by hG
  char* regA = base;
  us*    Wp    = (us*)   (regA + 0);          // 3,145,728 (fragment-linear Wc)
  float* biasc = (float*)(regA + 3145728);    // 8,192
  us*    h0    = (us*)   (regA + 3153920);    // 524,288
  float* cst   = (float*)(regA + 3678208);    // 1,048,576
  float* M1f   = (float*)(regA + 4726784);    // 524,288
  float* M2f   = (float*)(regA + 5251072);    // 524,288
  us*    xbf   = (us*)   (regA + 5775360);    // 16,777,216
  us*    hG    = (us*)   regA;                // 33,554,432 (after LSTM)
  // region B: survivors
  char* regB = base + 33554432;
  us*    Gc_w  = (us*)(regB + 0);             // 524,288
  us*    Gt_w  = (us*)(regB + 524288);        // 524,288
  us*    M1vh  = (us*)(regB + 1048576);       // 262,144
  us*    M1vl  = (us*)(regB + 1310720);       // 262,144
  us*    M2vh  = (us*)(regB + 1572864);       // 262,144
  us*    M2vl  = (us*)(regB + 1835008);       // 262,144
  float* u_c   = (float*)(regB + 2097152);    // 2,048
  float* u_t   = (float*)(regB + 2099200);    // 2,048
  float* p_c   = (float*)(regB + 2101248);    // 2,048
  float* p_t   = (float*)(regB + 2103296);    // 2,048
  float* bc    = (float*)(regB + 2105344);    // 1,024
  // region C: hs (b, t, e) bf16
  us*    hs    = (us*)(base + 33554432 + 2106368);  // 33,554,432
  unsigned* bars = (unsigned*)(base + 33554432 + 2106368 + 33554432); // 4,096

  static bool attr_done = false;
  if (!attr_done){
    hipFuncSetAttribute(reinterpret_cast<const void*>(&k_lstm_all2),
                        hipFuncAttributeMaxDynamicSharedMemorySize, 73728);
    attr_done = true;
  }

  // ---- prep ----
  hipMemsetAsync(bars, 0, 4096, stream);
  k_prep_wperm<<<2048, 768, 0, stream>>>(w_hh, w_ih, b_ih, b_hh, Wp, biasc);
  k_prep_state<<<1024, 256, 0, stream>>>(char_hn0, tag_hn0, char_cn0, tag_cn0, h0, cst);
  k_xprep<<<4096, 256, 0, stream>>>(true_out, xbf);
  k_pgemm<true,1><<<dim3(8,8),256,0,stream>>>(c_wk, 512, c_wq, 512, Gc_w, nullptr, 512, 512);
  k_pgemm<true,1><<<dim3(8,8),256,0,stream>>>(t_wk, 512, t_wq, 512, Gt_w, nullptr, 512, 512);
  k_pgemm<false,0><<<dim3(4,8),256,0,stream>>>(out_w,     1024, c_wo, 512, M1f, nullptr, 512, 512);
  k_pgemm<false,0><<<dim3(4,8),256,0,stream>>>(out_w+512, 1024, t_wo, 512, M2f, nullptr, 512, 512);
  k_pgemm<false,2><<<dim3(4,8),256,0,stream>>>(M1f, 512, c_wv, 512, M1vh, M1vl, 512, 512);
  k_pgemm<false,2><<<dim3(4,8),256,0,stream>>>(M2f, 512, t_wv, 512, M2vh, M2vl, 512, 512);
  k_uvec<<<4,128,0,stream>>>(c_bq, c_wk, u_c);
  k_uvec<<<4,128,0,stream>>>(t_bq, t_wk, u_t);
  k_pvec<<<4,128,0,stream>>>(c_wo, c_bv, c_bo, p_c);
  k_pvec<<<4,128,0,stream>>>(t_wo, t_bv, t_bo, p_t);
  k_bc<<<1,256,0,stream>>>(out_w, p_c, p_t, out_b, bc);

  // ---- LSTM: single persistent dispatch, 64 steps, 2 blocks/CU ----
  k_lstm_all2<<<512, 256, 73728, stream>>>(h0, xbf, Wp, biasc, cst, hs, bars);

  const float scale = 0.044194173824159216f;  // 1/sqrt(512)
  // ---- char attention ----
  k_gemm<<<dim3(256,4),256,0,stream>>>(hs, Gc_w, u_c, scale, hG);
  k_attn3<64,false><<<512,256,sizeof(ASmem3<64>),stream>>>(hG, char_enc, M1vh, M1vl, out);
  // ---- tag attention ----
  k_gemm<<<dim3(256,4),256,0,stream>>>(hs, Gt_w, u_t, scale, hG);
  k_attn3<16,true ><<<512,256,sizeof(ASmem3<16>),stream>>>(hG, tag_enc, M2vh, M2vl, out);
  // ---- entmax-1.5 ----
  k_entmax<<<2048,256,0,stream>>>(out, bc);
}

// Round 6
// 1120.533 us; speedup vs baseline: 1.1291x; 1.1291x over previous
//
#include <hip/hip_runtime.h>

typedef unsigned short us;
typedef unsigned int u32;
typedef unsigned long long u64;
typedef __bf16 bf16x8 __attribute__((ext_vector_type(8)));
typedef float f32x4 __attribute__((ext_vector_type(4)));

#define MFMA(a,b,c) __builtin_amdgcn_mfma_f32_16x16x32_bf16(a,b,c,0,0,0)

__device__ __forceinline__ us f2bf(float f){
  u32 u = __builtin_bit_cast(u32, f);
  u += 0x7fffu + ((u>>16)&1u);
  return (us)(u>>16);
}
__device__ __forceinline__ float bf2f(us h){
  u32 u = ((u32)h)<<16;
  return __builtin_bit_cast(float, u);
}
__device__ __forceinline__ float sigf(float x){ return 1.0f/(1.0f+__expf(-x)); }
__device__ __forceinline__ float tanh_(float x){ float e=__expf(2.0f*x); return 1.0f - 2.0f/(e+1.0f); }

// ---------------- prep kernels ----------------

// Wc permuted to MFMA-fragment-linear order per 16-e slice:
// dst us index: (((eb*24 + kc)*4 + g)*64 + qd*16 + ln)*8 + i
__global__ void k_prep_wperm(const float* __restrict__ w_hh, const float* __restrict__ w_ih,
                             const float* __restrict__ b_ih, const float* __restrict__ b_hh,
                             us* __restrict__ Wp, float* __restrict__ biasc){
  int n = blockIdx.x; int c = threadIdx.x;          // n<2048, c<768
  float v = (c < 512) ? w_hh[(size_t)n*512 + c] : w_ih[(size_t)n*256 + (c-512)];
  int g = n >> 9, eg = n & 511, eb = eg >> 4, ln = eg & 15;
  int kc = c >> 5, qd = (c >> 3) & 3, i = c & 7;
  size_t dst = ((((size_t)eb*24 + kc)*4 + g)*64 + (size_t)(qd*16 + ln))*8 + i;
  Wp[dst] = f2bf(v);
  if (c == 0) biasc[n] = b_ih[n] + b_hh[n];
}

__global__ void k_prep_state(const float* __restrict__ ch, const float* __restrict__ th,
                             const float* __restrict__ cc, const float* __restrict__ tc,
                             us* __restrict__ h0, float* __restrict__ c0){
  int i = blockIdx.x*256 + threadIdx.x;   // 262144
  int b = i>>9, e = i&511;
  float hv = (e<256)? ch[b*256+e] : th[b*256+e-256];
  float cv = (e<256)? cc[b*256+e] : tc[b*256+e-256];
  h0[i] = f2bf(hv); c0[i] = cv;
}

// xbf[t][b][v] = bf16(true_output[b][t][v])
__global__ void k_xprep(const float* __restrict__ x, us* __restrict__ xbf){
  int g = blockIdx.x*256 + threadIdx.x;      // 1,048,576 groups of 8 elements
  int v0 = (g & 31) * 8;
  int b  = (g >> 5) & 511;
  int t  = g >> 14;
  const float4* src = (const float4*)(x + ((size_t)(b*64 + t))*256 + v0);
  float4 f0 = src[0], f1 = src[1];
  uint4 pk;
  pk.x = (u32)f2bf(f0.x) | ((u32)f2bf(f0.y)<<16);
  pk.y = (u32)f2bf(f0.z) | ((u32)f2bf(f0.w)<<16);
  pk.z = (u32)f2bf(f1.x) | ((u32)f2bf(f1.y)<<16);
  pk.w = (u32)f2bf(f1.z) | ((u32)f2bf(f1.w)<<16);
  *(uint4*)(xbf + ((size_t)t*512 + b)*256 + v0) = pk;
}

// u[j] = sum_e bq[e]*wk[e][j]
__global__ void k_uvec(const float* __restrict__ bq, const float* __restrict__ wk,
                       float* __restrict__ u){
  int j = blockIdx.x*128 + threadIdx.x;
  float a = 0.f;
  for (int e=0;e<512;++e) a += bq[e]*wk[(size_t)e*512 + j];
  u[j] = a;
}

// p[i] = sum_j wo[i][j]*bv[j] + bo[i]
__global__ void k_pvec(const float* __restrict__ wo, const float* __restrict__ bv,
                       const float* __restrict__ bo, float* __restrict__ p){
  int i = blockIdx.x*128 + threadIdx.x;
  float a = bo[i];
  for (int j=0;j<512;++j) a += wo[(size_t)i*512+j]*bv[j];
  p[i] = a;
}

// bc[v] = out_b[v] + out_w[v,:512]@pc + out_w[v,512:]@pt
__global__ void k_bc(const float* __restrict__ out_w, const float* __restrict__ pc,
                     const float* __restrict__ pt, const float* __restrict__ out_b,
                     float* __restrict__ bc){
  int v = threadIdx.x;
  float a = out_b[v];
  for (int i=0;i<512;++i) a += out_w[(size_t)v*1024+i]*pc[i];
  for (int i=0;i<512;++i) a += out_w[(size_t)v*1024+512+i]*pt[i];
  bc[v] = a;
}

// ---- small MFMA prep GEMM ----
template<bool TA, int OMODE>
__global__ __launch_bounds__(256) void k_pgemm(const float* __restrict__ A, int lda,
    const float* __restrict__ B, int ldb, void* C1, void* C2, int ldc, int K){
  __shared__ us As[64][40];
  __shared__ us Bs[64][40];
  int tid=threadIdx.x, w=tid>>6, lane=tid&63, qd=lane>>4, ln=lane&15;
  int m0 = blockIdx.x*64, n0 = blockIdx.y*64;
  f32x4 acc[4] = {};
  for (int kc=0; kc<K/32; ++kc){
    int k0 = kc*32;
    if (!TA){
      int r=tid>>2, c=(tid&3)*8;
      const float* ap = A + (size_t)(m0+r)*lda + k0 + c;
      float4 f0=*(const float4*)ap, f1=*(const float4*)(ap+4);
      uint4 pk;
      pk.x=(u32)f2bf(f0.x)|((u32)f2bf(f0.y)<<16);
      pk.y=(u32)f2bf(f0.z)|((u32)f2bf(f0.w)<<16);
      pk.z=(u32)f2bf(f1.x)|((u32)f2bf(f1.y)<<16);
      pk.w=(u32)f2bf(f1.z)|((u32)f2bf(f1.w)<<16);
      *(uint4*)&As[r][c] = pk;
    } else {
      int kk=tid>>3, mp=(tid&7)*8;
      const float* ap = A + (size_t)(k0+kk)*lda + m0 + mp;
      #pragma unroll
      for (int i=0;i<8;++i) As[mp+i][kk] = f2bf(ap[i]);
    }
    { int kk=tid>>3, np=(tid&7)*8;
      const float* bp = B + (size_t)(k0+kk)*ldb + n0 + np;
      #pragma unroll
      for (int i=0;i<8;++i) Bs[np+i][kk] = f2bf(bp[i]);
    }
    __syncthreads();
    bf16x8 a = *(const bf16x8*)&As[16*w+ln][qd*8];
    #pragma unroll
    for (int j=0;j<4;++j){
      bf16x8 bb = *(const bf16x8*)&Bs[16*j+ln][qd*8];
      acc[j] = MFMA(a, bb, acc[j]);
    }
    __syncthreads();
  }
  #pragma unroll
  for (int j=0;j<4;++j){
    #pragma unroll
    for (int r=0;r<4;++r){
      size_t idx = (size_t)(m0+16*w+qd*4+r)*ldc + (n0+16*j+ln);
      float v = acc[j][r];
      if (OMODE==0) ((float*)C1)[idx] = v;
      else if (OMODE==1) ((us*)C1)[idx] = f2bf(v);
      else {
        us h = f2bf(v);
        ((us*)C1)[idx] = h;
        ((us*)C2)[idx] = f2bf(v - bf2f(h));
      }
    }
  }
}

// ---------------- persistent LSTM v4 (r4 structure + flag-array barrier) ----
// 256 blocks = 32 e-slices x 8 b-tiles (64 rows). W slice (incl. x-part) in
// LDS for the whole kernel. c-state in registers. h exchange fence-free
// (relaxed agent-scope 8B atomic stores/loads, r4).
// Barrier: NO shared counter (32-way RMW on one line serialized ~4-5us/step).
// Each block stores its OWN flag (64B stride, one writer per line); readers
// poll all 32 flags in parallel (lane i loads flag i) -> one L3 latency per
// poll iteration, zero RMW.
__global__ __launch_bounds__(256, 1) void k_lstm_all(
    const us* __restrict__ h0, const us* __restrict__ xbf,
    const us* __restrict__ Wp, const float* __restrict__ biasc,
    const float* __restrict__ c0, us* __restrict__ hs,
    unsigned* __restrict__ bars){
  extern __shared__ us Wf[];  // [24][4][64][8] us = 98304 B
  int tid = threadIdx.x, w = tid>>6, lane = tid&63, qd = lane>>4, ln = lane&15;
  int bb = blockIdx.x & 7, eb = blockIdx.x >> 3;
  int b0 = bb*64, e0 = eb*16;
  // load W slice (98 KB) once, coalesced
  {
    const uint4* src = (const uint4*)(Wp + (size_t)eb*49152);
    uint4* dst = (uint4*)Wf;
    #pragma unroll
    for (int i=0;i<24;++i) dst[tid + 256*i] = src[tid + 256*i];
  }
  int bA = b0 + 16*w + ln;      // row for A-fragment loads
  int bC = b0 + 16*w + qd*4;    // rows for cell update (+r)
  int e  = e0 + ln;
  float bias_[4], c_[4];
  #pragma unroll
  for (int j=0;j<4;++j) bias_[j] = biasc[j*512 + e];
  #pragma unroll
  for (int r=0;r<4;++r) c_[r] = c0[(size_t)(bC+r)*512 + e];
  __syncthreads();
  unsigned* flags = bars + (size_t)bb*512;   // 2KB per group; flag eb at 64B stride
  unsigned* myflag = flags + eb*16;
  const unsigned* pollp = flags + (lane&31)*16;
  f32x4 xacc[4] = {};             // x-part of gates for current step (x_0 = 0)
  for (int t=0; t<64; ++t){
    if (t > 0){
      // wait until every block in this b-group has published h_{t-1}:
      // 32 lanes poll the 32 flags in parallel (reads only, no RMW)
      unsigned tgt = (unsigned)t;
      while (true){
        unsigned v = __hip_atomic_load(pollp, __ATOMIC_RELAXED, __HIP_MEMORY_SCOPE_AGENT);
        if (__all((int)(v >= tgt))) break;
        __builtin_amdgcn_s_sleep(1);
      }
      // no fence: h loads below are agent-scope atomic (coherence-point) loads
    }
    bf16x8 afr[16];
    if (t == 0){
      const us* hrow = h0 + (size_t)bA*512;   // prep output: cached loads fine
      #pragma unroll
      for (int kc=0; kc<16; ++kc)
        afr[kc] = *(const bf16x8*)(hrow + kc*32 + qd*8);
    } else {
      const u64* hq = (const u64*)(hs + ((size_t)bA*64 + (t-1))*512);
      u64 q0[16], q1[16];
      #pragma unroll
      for (int kc=0; kc<16; ++kc){
        q0[kc] = __hip_atomic_load(hq + kc*8 + qd*2 + 0, __ATOMIC_RELAXED, __HIP_MEMORY_SCOPE_AGENT);
        q1[kc] = __hip_atomic_load(hq + kc*8 + qd*2 + 1, __ATOMIC_RELAXED, __HIP_MEMORY_SCOPE_AGENT);
      }
      #pragma unroll
      for (int kc=0; kc<16; ++kc){
        union { u64 q[2]; bf16x8 v; } u_;
        u_.q[0] = q0[kc]; u_.q[1] = q1[kc];
        afr[kc] = u_.v;
      }
    }
    f32x4 acc[4] = {xacc[0], xacc[1], xacc[2], xacc[3]};
    #pragma unroll
    for (int kc=0; kc<16; ++kc){
      #pragma unroll
      for (int j=0;j<4;++j){
        bf16x8 bfrag = *(const bf16x8*)&Wf[(size_t)((kc*4+j)*64 + lane)*8];
        acc[j] = MFMA(afr[kc], bfrag, acc[j]);
      }
    }
    // cell update: lane holds i,f,g,o for (b = bC+r, e)
    us hb[4];
    #pragma unroll
    for (int r=0;r<4;++r){
      float iv = acc[0][r]+bias_[0], fv = acc[1][r]+bias_[1];
      float gv = acc[2][r]+bias_[2], ov = acc[3][r]+bias_[3];
      float cc2 = sigf(fv)*c_[r] + sigf(iv)*tanh_(gv);
      c_[r] = cc2;
      hb[r] = f2bf(sigf(ov)*tanh_(cc2));
    }
    // pack 4 lanes' bf16 into 8B, write-through store (agent-scope atomic)
    #pragma unroll
    for (int r=0;r<4;++r){
      u32 v = hb[r];
      u32 p = v | (((u32)__shfl_xor((int)v, 1)) << 16);
      u64 q = (u64)p | (((u64)(u32)__shfl_xor((int)p, 2)) << 32);
      if ((lane & 3) == 0){
        size_t idx = ((size_t)(bC+r)*64 + t)*512 + e0 + ln;   // ln multiple of 4 here
        __hip_atomic_store((u64*)(hs + idx), q, __ATOMIC_RELAXED, __HIP_MEMORY_SCOPE_AGENT);
      }
    }
    if (t < 63){
      __syncthreads();   // drains vmcnt(0): h stores are at L3 before the flag
      if (tid == 0)
        __hip_atomic_store(myflag, (unsigned)(t+1), __ATOMIC_RELAXED, __HIP_MEMORY_SCOPE_AGENT);
      // overlap: x-part of gates for step t+1 (independent of h_t)
      const us* xrow = xbf + ((size_t)(t+1)*512 + bA)*256;
      f32x4 xa[4] = {};
      #pragma unroll
      for (int kx=0; kx<8; ++kx){
        bf16x8 xf = *(const bf16x8*)(xrow + kx*32 + qd*8);
        #pragma unroll
        for (int j=0;j<4;++j){
          bf16x8 bfrag = *(const bf16x8*)&Wf[(size_t)(((16+kx)*4+j)*64 + lane)*8];
          xa[j] = MFMA(xf, bfrag, xa[j]);
        }
      }
      #pragma unroll
      for (int j=0;j<4;++j) xacc[j] = xa[j];
    }
  }
}

// ------- C = bf16(alpha*(A @ W^T + bias)), A bf16 (M x 512), W bf16 (N x 512) -------
__global__ __launch_bounds__(256) void k_gemm(
    const us* __restrict__ Ap, const us* __restrict__ W,
    const float* __restrict__ bias, float alpha, us* __restrict__ C){
  __shared__ us As[128][40];
  __shared__ us Ws[128][40];
  int tid = threadIdx.x; int w = tid>>6; int lane=tid&63;
  int qd=lane>>4, ln=lane&15;
  int m0 = blockIdx.x*128, n0 = blockIdx.y*128;
  int wm = (w&1)*64, wn=(w>>1)*64;
  f32x4 acc[4][4] = {};
  int row = tid>>1; int cp = (tid&1)*16;
  for (int kc=0;kc<16;++kc){
    int k0=kc*32;
    { const uint4* ap = (const uint4*)(Ap + (size_t)(m0+row)*512 + k0+cp);
      *(uint4*)&As[row][cp]=ap[0]; *(uint4*)&As[row][cp+8]=ap[1];
    }
    { const uint4* wp = (const uint4*)(W + (size_t)(n0+row)*512 + k0+cp);
      *(uint4*)&Ws[row][cp]=wp[0]; *(uint4*)&Ws[row][cp+8]=wp[1];
    }
    __syncthreads();
    bf16x8 af[4], bfr[4];
    #pragma unroll
    for (int i=0;i<4;++i) af[i]  = *(const bf16x8*)&As[wm+16*i+ln][qd*8];
    #pragma unroll
    for (int j=0;j<4;++j) bfr[j] = *(const bf16x8*)&Ws[wn+16*j+ln][qd*8];
    #pragma unroll
    for (int i=0;i<4;++i)
      #pragma unroll
      for (int j=0;j<4;++j) acc[i][j]=MFMA(af[i],bfr[j],acc[i][j]);
    __syncthreads();
  }
  #pragma unroll
  for (int j=0;j<4;++j){
    int col = n0+wn+16*j+ln;
    float bv = bias[col];
    #pragma unroll
    for (int i=0;i<4;++i){
      #pragma unroll
      for (int r=0;r<4;++r){
        int rm = m0+wm+16*i+qd*4+r;
        C[(size_t)rm*512 + col] = f2bf(alpha*(acc[i][j][r]+bv));
      }
    }
  }
}

// ---------------- fused attention + output projection (v3) ----------------
template<int S>
struct alignas(16) ASmem3 {
  static constexpr int SP  = (S<32)?32:S;
  static constexpr int SPp = SP+8;
  us Pbh[64][SPp];
  us Pbl[64][SPp];
  union {
    us Es[S][72];
    struct { us Eh[64][72]; us El[64][72]; } t;
  } u;
  us Ph[64][72];
  us Pl[64][72];
};

template<int S, bool ACC>
__global__ __launch_bounds__(256) void k_attn3(const us* __restrict__ hGp,
    const float* __restrict__ enc, const us* __restrict__ Mvh,
    const us* __restrict__ Mvl, float* __restrict__ out){
  constexpr int NJ  = S/16;
  constexpr int KC2 = ((S<32)?32:S)/32;
  extern __shared__ char smraw[];
  ASmem3<S>& sm = *reinterpret_cast<ASmem3<S>*>(smraw);
  int b = blockIdx.x;
  int tid=threadIdx.x, w=tid>>6, lane=tid&63, qd=lane>>4, ln=lane&15;

  // ---- phase 1: S = hG @ enc^T ----
  f32x4 sacc[NJ];
  #pragma unroll
  for (int j=0;j<NJ;++j) sacc[j] = (f32x4){0.f,0.f,0.f,0.f};
  const us* hrow = hGp + ((size_t)(b*64 + 16*w + ln))*512;
  for (int ec=0; ec<8; ++ec){
    int e0 = ec*64;
    { int s = tid>>2, ep=(tid&3)*16;
      if (S==64 || tid < 4*S){
        const float* ap = enc + ((size_t)b*S + s)*512 + e0 + ep;
        float4 f0=*(const float4*)ap, f1=*(const float4*)(ap+4);
        float4 f2=*(const float4*)(ap+8), f3=*(const float4*)(ap+12);
        float fv[16]={f0.x,f0.y,f0.z,f0.w,f1.x,f1.y,f1.z,f1.w,
                      f2.x,f2.y,f2.z,f2.w,f3.x,f3.y,f3.z,f3.w};
        u32 pk[8];
        #pragma unroll
        for (int i=0;i<8;++i)
          pk[i] = (u32)f2bf(fv[2*i]) | ((u32)f2bf(fv[2*i+1])<<16);
        uint4* d = (uint4*)&sm.u.Es[s][ep];
        d[0] = make_uint4(pk[0],pk[1],pk[2],pk[3]);
        d[1] = make_uint4(pk[4],pk[5],pk[6],pk[7]);
      }
    }
    __syncthreads();
    #pragma unroll
    for (int kcl=0;kcl<2;++kcl){
      bf16x8 a = *(const bf16x8*)(hrow + e0 + kcl*32 + qd*8);
      #pragma unroll
      for (int j=0;j<NJ;++j){
        bf16x8 bb = *(const bf16x8*)&sm.u.Es[16*j+ln][kcl*32+qd*8];
        sacc[j] = MFMA(a, bb, sacc[j]);
      }
    }
    __syncthreads();
  }

  // ---- softmax, fully in-register ----
  #pragma unroll
  for (int r=0;r<4;++r){
    float m = sacc[0][r];
    #pragma unroll
    for (int j=1;j<NJ;++j) m = fmaxf(m, sacc[j][r]);
    #pragma unroll
    for (int dl=1; dl<16; dl<<=1) m = fmaxf(m, __shfl_xor(m, dl));
    float ssum = 0.f;
    #pragma unroll
    for (int j=0;j<NJ;++j){ float e_=__expf(sacc[j][r]-m); sacc[j][r]=e_; ssum+=e_; }
    #pragma unroll
    for (int dl=1; dl<16; dl<<=1) ssum += __shfl_xor(ssum, dl);
    float inv = 1.0f/ssum;
    int R = 16*w + qd*4 + r;
    #pragma unroll
    for (int j=0;j<NJ;++j){
      float pv = sacc[j][r]*inv;
      us h = f2bf(pv);
      sm.Pbh[R][16*j+ln] = h;
      sm.Pbl[R][16*j+ln] = f2bf(pv - bf2f(h));
    }
    if (S==16){ sm.Pbh[R][16+ln]=0; sm.Pbl[R][16+ln]=0; }
  }

  // ---- phase 2 ----
  f32x4 Lacc[4][4] = {};
  for (int ec=0; ec<8; ++ec){
    int e0 = ec*64;
    { int s = tid>>2, ep=(tid&3)*16;
      if (S==64 || tid < 4*S){
        const float* ap = enc + ((size_t)b*S + s)*512 + e0 + ep;
        float4 f0=*(const float4*)ap, f1=*(const float4*)(ap+4);
        float4 f2=*(const float4*)(ap+8), f3=*(const float4*)(ap+12);
        float fv[16]={f0.x,f0.y,f0.z,f0.w,f1.x,f1.y,f1.z,f1.w,
                      f2.x,f2.y,f2.z,f2.w,f3.x,f3.y,f3.z,f3.w};
        #pragma unroll
        for (int i=0;i<16;++i){
          float v = fv[i]; us h = f2bf(v);
          sm.u.t.Eh[ep+i][s] = h;
          sm.u.t.El[ep+i][s] = f2bf(v - bf2f(h));
        }
      } else if (S==16 && tid < 128){
        int s2 = 16 + ((tid-64)>>2);
        #pragma unroll
        for (int i=0;i<16;++i){ sm.u.t.Eh[ep+i][s2]=0; sm.u.t.El[ep+i][s2]=0; }
      }
    }
    __syncthreads();
    f32x4 pacc[4] = {};
    #pragma unroll
    for (int kcl=0;kcl<KC2;++kcl){
      bf16x8 ah = *(const bf16x8*)&sm.Pbh[16*w+ln][kcl*32+qd*8];
      bf16x8 al = *(const bf16x8*)&sm.Pbl[16*w+ln][kcl*32+qd*8];
      #pragma unroll
      for (int j=0;j<4;++j){
        bf16x8 bh = *(const bf16x8*)&sm.u.t.Eh[16*j+ln][kcl*32+qd*8];
        bf16x8 bl = *(const bf16x8*)&sm.u.t.El[16*j+ln][kcl*32+qd*8];
        pacc[j] = MFMA(ah, bh, pacc[j]);
        pacc[j] = MFMA(ah, bl, pacc[j]);
        pacc[j] = MFMA(al, bh, pacc[j]);
      }
    }
    #pragma unroll
    for (int j=0;j<4;++j)
      #pragma unroll
      for (int r=0;r<4;++r){
        float v = pacc[j][r]; us h = f2bf(v);
        sm.Ph[16*w+qd*4+r][16*j+ln] = h;
        sm.Pl[16*w+qd*4+r][16*j+ln] = f2bf(v - bf2f(h));
      }
    __syncthreads();
    #pragma unroll
    for (int kcl=0;kcl<2;++kcl){
      bf16x8 ah[4], al[4];
      #pragma unroll
      for (int i=0;i<4;++i){
        ah[i] = *(const bf16x8*)&sm.Ph[16*i+ln][kcl*32+qd*8];
        al[i] = *(const bf16x8*)&sm.Pl[16*i+ln][kcl*32+qd*8];
      }
      #pragma unroll
      for (int j=0;j<4;++j){
        int v = 64*w + 16*j + ln;
        bf16x8 mh = *(const bf16x8*)(Mvh + (size_t)v*512 + e0 + kcl*32 + qd*8);
        bf16x8 ml = *(const bf16x8*)(Mvl + (size_t)v*512 + e0 + kcl*32 + qd*8);
        #pragma unroll
        for (int i=0;i<4;++i){
          Lacc[i][j] = MFMA(ah[i], mh, Lacc[i][j]);
          Lacc[i][j] = MFMA(ah[i], ml, Lacc[i][j]);
          Lacc[i][j] = MFMA(al[i], mh, Lacc[i][j]);
        }
      }
    }
  }
  // epilogue
  #pragma unroll
  for (int i=0;i<4;++i){
    #pragma unroll
    for (int j=0;j<4;++j){
      int v = 64*w + 16*j + ln;
      #pragma unroll
      for (int r=0;r<4;++r){
        size_t addr = ((size_t)b*64 + 16*i + qd*4 + r)*256 + v;
        if (ACC) out[addr] += Lacc[i][j][r];
        else     out[addr]  = Lacc[i][j][r];
      }
    }
  }
}

// ---------------- entmax-1.5 in place over rows of 256 ----------------
__global__ __launch_bounds__(256) void k_entmax(float* __restrict__ out,
                                                const float* __restrict__ bc){
  int tid=threadIdx.x; int w=tid>>6; int lane=tid&63;
  float4 bcv = *(const float4*)(bc + lane*4);
  int base = blockIdx.x*16 + w*4;
  for (int i=0;i<4;++i){
    int row = base + i;
    float* rp = out + (size_t)row*256 + lane*4;
    float4 d = *(const float4*)rp;
    float z[4] = {0.5f*(d.x+bcv.x), 0.5f*(d.y+bcv.y), 0.5f*(d.z+bcv.z), 0.5f*(d.w+bcv.w)};
    float m = fmaxf(fmaxf(z[0],z[1]), fmaxf(z[2],z[3]));
    #pragma unroll
    for (int dl=1; dl<64; dl<<=1) m = fmaxf(m, __shfl_xor(m, dl));
    #pragma unroll
    for (int k=0;k<4;++k) z[k] -= m;
    float tau = -1.0f;
    for (int it=0; it<14; ++it){
      float s1=0.f, s2=0.f;
      #pragma unroll
      for (int k=0;k<4;++k){
        float dd = z[k]-tau; dd = fmaxf(dd, 0.f);
        s1 += dd; s2 += dd*dd;
      }
      #pragma unroll
      for (int dl=1; dl<64; dl<<=1){ s1 += __shfl_xor(s1, dl); s2 += __shfl_xor(s2, dl); }
      tau += (s2 - 1.0f) / (2.0f*fmaxf(s1, 1e-12f));
    }
    float4 y;
    { float dd;
      dd = fmaxf(z[0]-tau,0.f); y.x = dd*dd;
      dd = fmaxf(z[1]-tau,0.f); y.y = dd*dd;
      dd = fmaxf(z[2]-tau,0.f); y.z = dd*dd;
      dd = fmaxf(z[3]-tau,0.f); y.w = dd*dd;
    }
    *(float4*)rp = y;
  }
}

// ---------------- launch ----------------

extern "C" void kernel_launch(void* const* d_in, const int* in_sizes, int n_in,
                              void* d_out, int out_size, void* d_ws, size_t ws_size,
                              hipStream_t stream){
  (void)in_sizes; (void)n_in; (void)out_size; (void)ws_size;
  const float* char_enc = (const float*)d_in[0];
  const float* char_hn0 = (const float*)d_in[1];
  const float* char_cn0 = (const float*)d_in[2];
  const float* tag_enc  = (const float*)d_in[3];
  const float* tag_hn0  = (const float*)d_in[4];
  const float* tag_cn0  = (const float*)d_in[5];
  const float* true_out = (const float*)d_in[6];
  const float* w_ih = (const float*)d_in[7];
  const float* w_hh = (const float*)d_in[8];
  const float* b_ih = (const float*)d_in[9];
  const float* b_hh = (const float*)d_in[10];
  const float* c_wq = (const float*)d_in[11];
  const float* c_wk = (const float*)d_in[12];
  const float* c_wv = (const float*)d_in[13];
  const float* c_bq = (const float*)d_in[14];
  const float* c_bv = (const float*)d_in[16];
  const float* c_wo = (const float*)d_in[17];
  const float* c_bo = (const float*)d_in[18];
  const float* t_wq = (const float*)d_in[19];
  const float* t_wk = (const float*)d_in[20];
  const float* t_wv = (const float*)d_in[21];
  const float* t_bq = (const float*)d_in[22];
  const float* t_bv = (const float*)d_in[24];
  const float* t_wo = (const float*)d_in[25];
  const float* t_bo = (const float*)d_in[26];
  const float* out_w = (const float*)d_in[27];
  const float* out_b = (const float*)d_in[28];
  float* out = (float*)d_out;

  char* base = (char*)d_ws;
  // region A: prep/LSTM scratch, later overwritten by hG
  char* regA = base;
  us*    Wp    = (us*)   (regA + 0);          // 3,145,728 (fragment-linear Wc)
  float* biasc = (float*)(regA + 3145728);    // 8,192
  us*    h0    = (us*)   (regA + 3153920);    // 524,288
  float* cst   = (float*)(regA + 3678208);    // 1,048,576
  float* M1f   = (float*)(regA + 4726784);    // 524,288
  float* M2f   = (float*)(regA + 5251072);    // 524,288
  us*    xbf   = (us*)   (regA + 5775360);    // 16,777,216
  us*    hG    = (us*)   regA;                // 33,554,432 (after LSTM)
  // region B: survivors
  char* regB = base + 33554432;
  us*    Gc_w  = (us*)(regB + 0);             // 524,288
  us*    Gt_w  = (us*)(regB + 524288);        // 524,288
  us*    M1vh  = (us*)(regB + 1048576);       // 262,144
  us*    M1vl  = (us*)(regB + 1310720);       // 262,144
  us*    M2vh  = (us*)(regB + 1572864);       // 262,144
  us*    M2vl  = (us*)(regB + 1835008);       // 262,144
  float* u_c   = (float*)(regB + 2097152);    // 2,048
  float* u_t   = (float*)(regB + 2099200);    // 2,048
  float* p_c   = (float*)(regB + 2101248);    // 2,048
  float* p_t   = (float*)(regB + 2103296);    // 2,048
  float* bc    = (float*)(regB + 2105344);    // 1,024
  // region C: hs (b, t, e) bf16
  us*    hs    = (us*)(base + 33554432 + 2106368);  // 33,554,432
  unsigned* bars = (unsigned*)(base + 33554432 + 2106368 + 33554432); // 16,384

  static bool attr_done = false;
  if (!attr_done){
    hipFuncSetAttribute(reinterpret_cast<const void*>(&k_lstm_all),
                        hipFuncAttributeMaxDynamicSharedMemorySize, 131072);
    attr_done = true;
  }

  // ---- prep ----
  hipMemsetAsync(bars, 0, 16384, stream);
  k_prep_wperm<<<2048, 768, 0, stream>>>(w_hh, w_ih, b_ih, b_hh, Wp, biasc);
  k_prep_state<<<1024, 256, 0, stream>>>(char_hn0, tag_hn0, char_cn0, tag_cn0, h0, cst);
  k_xprep<<<4096, 256, 0, stream>>>(true_out, xbf);
  k_pgemm<true,1><<<dim3(8,8),256,0,stream>>>(c_wk, 512, c_wq, 512, Gc_w, nullptr, 512, 512);
  k_pgemm<true,1><<<dim3(8,8),256,0,stream>>>(t_wk, 512, t_wq, 512, Gt_w, nullptr, 512, 512);
  k_pgemm<false,0><<<dim3(4,8),256,0,stream>>>(out_w,     1024, c_wo, 512, M1f, nullptr, 512, 512);
  k_pgemm<false,0><<<dim3(4,8),256,0,stream>>>(out_w+512, 1024, t_wo, 512, M2f, nullptr, 512, 512);
  k_pgemm<false,2><<<dim3(4,8),256,0,stream>>>(M1f, 512, c_wv, 512, M1vh, M1vl, 512, 512);
  k_pgemm<false,2><<<dim3(4,8),256,0,stream>>>(M2f, 512, t_wv, 512, M2vh, M2vl, 512, 512);
  k_uvec<<<4,128,0,stream>>>(c_bq, c_wk, u_c);
  k_uvec<<<4,128,0,stream>>>(t_bq, t_wk, u_t);
  k_pvec<<<4,128,0,stream>>>(c_wo, c_bv, c_bo, p_c);
  k_pvec<<<4,128,0,stream>>>(t_wo, t_bv, t_bo, p_t);
  k_bc<<<1,256,0,stream>>>(out_w, p_c, p_t, out_b, bc);

  // ---- LSTM: single persistent dispatch, 64 steps ----
  k_lstm_all<<<256, 256, 98304, stream>>>(h0, xbf, Wp, biasc, cst, hs, bars);

  const float scale = 0.044194173824159216f;  // 1/sqrt(512)
  // ---- char attention ----
  k_gemm<<<dim3(256,4),256,0,stream>>>(hs, Gc_w, u_c, scale, hG);
  k_attn3<64,false><<<512,256,sizeof(ASmem3<64>),stream>>>(hG, char_enc, M1vh, M1vl, out);
  // ---- tag attention ----
  k_gemm<<<dim3(256,4),256,0,stream>>>(hs, Gt_w, u_t, scale, hG);
  k_attn3<16,true ><<<512,256,sizeof(ASmem3<16>),stream>>>(hG, tag_enc, M2vh, M2vl, out);
  // ---- entmax-1.5 ----
  k_entmax<<<2048,256,0,stream>>>(out, bc);
}

// Round 8
// 963.715 us; speedup vs baseline: 1.3128x; 1.1627x over previous
//
#include <hip/hip_runtime.h>

typedef unsigned short us;
typedef unsigned int u32;
typedef unsigned long long u64;
typedef __bf16 bf16x8 __attribute__((ext_vector_type(8)));
typedef float f32x4 __attribute__((ext_vector_type(4)));

#define MFMA(a,b,c) __builtin_amdgcn_mfma_f32_16x16x32_bf16(a,b,c,0,0,0)

__device__ __forceinline__ us f2bf(float f){
  u32 u = __builtin_bit_cast(u32, f);
  u += 0x7fffu + ((u>>16)&1u);
  return (us)(u>>16);
}
__device__ __forceinline__ float bf2f(us h){
  u32 u = ((u32)h)<<16;
  return __builtin_bit_cast(float, u);
}
__device__ __forceinline__ float sigf(float x){ return 1.0f/(1.0f+__expf(-x)); }
__device__ __forceinline__ float tanh_(float x){ float e=__expf(2.0f*x); return 1.0f - 2.0f/(e+1.0f); }

// ---------------- prep kernels ----------------

// Wc permuted to MFMA-fragment-linear order per 16-e slice:
// dst us index: (((eb*24 + kc)*4 + g)*64 + qd*16 + ln)*8 + i
__global__ void k_prep_wperm(const float* __restrict__ w_hh, const float* __restrict__ w_ih,
                             const float* __restrict__ b_ih, const float* __restrict__ b_hh,
                             us* __restrict__ Wp, float* __restrict__ biasc){
  int n = blockIdx.x; int c = threadIdx.x;          // n<2048, c<768
  float v = (c < 512) ? w_hh[(size_t)n*512 + c] : w_ih[(size_t)n*256 + (c-512)];
  int g = n >> 9, eg = n & 511, eb = eg >> 4, ln = eg & 15;
  int kc = c >> 5, qd = (c >> 3) & 3, i = c & 7;
  size_t dst = ((((size_t)eb*24 + kc)*4 + g)*64 + (size_t)(qd*16 + ln))*8 + i;
  Wp[dst] = f2bf(v);
  if (c == 0) biasc[n] = b_ih[n] + b_hh[n];
}

__global__ void k_prep_state(const float* __restrict__ ch, const float* __restrict__ th,
                             const float* __restrict__ cc, const float* __restrict__ tc,
                             us* __restrict__ h0, float* __restrict__ c0){
  int i = blockIdx.x*256 + threadIdx.x;   // 262144
  int b = i>>9, e = i&511;
  float hv = (e<256)? ch[b*256+e] : th[b*256+e-256];
  float cv = (e<256)? cc[b*256+e] : tc[b*256+e-256];
  h0[i] = f2bf(hv); c0[i] = cv;
}

// xbf[t][b][v] = bf16(true_output[b][t][v])
__global__ void k_xprep(const float* __restrict__ x, us* __restrict__ xbf){
  int g = blockIdx.x*256 + threadIdx.x;      // 1,048,576 groups of 8 elements
  int v0 = (g & 31) * 8;
  int b  = (g >> 5) & 511;
  int t  = g >> 14;
  const float4* src = (const float4*)(x + ((size_t)(b*64 + t))*256 + v0);
  float4 f0 = src[0], f1 = src[1];
  uint4 pk;
  pk.x = (u32)f2bf(f0.x) | ((u32)f2bf(f0.y)<<16);
  pk.y = (u32)f2bf(f0.z) | ((u32)f2bf(f0.w)<<16);
  pk.z = (u32)f2bf(f1.x) | ((u32)f2bf(f1.y)<<16);
  pk.w = (u32)f2bf(f1.z) | ((u32)f2bf(f1.w)<<16);
  *(uint4*)(xbf + ((size_t)t*512 + b)*256 + v0) = pk;
}

// u[j] += sum_{e in chunk} bq[e]*wk[e][j]   (u pre-zeroed; grid (2 j-tiles, 8 e-chunks))
__global__ void k_uvec2(const float* __restrict__ bq, const float* __restrict__ wk,
                        float* __restrict__ u){
  int j = blockIdx.x*256 + threadIdx.x;
  int e0 = blockIdx.y*64;
  float a = 0.f;
  #pragma unroll 8
  for (int e=e0; e<e0+64; ++e) a += bq[e]*wk[(size_t)e*512 + j];
  atomicAdd(u+j, a);
}

// p[i] = wo[i,:] . bv + bo[i]; one wave per row (grid 128 x 256thr)
__global__ __launch_bounds__(256) void k_pvec2(const float* __restrict__ wo,
    const float* __restrict__ bv, const float* __restrict__ bo, float* __restrict__ p){
  int w = threadIdx.x>>6, lane = threadIdx.x&63;
  int i = blockIdx.x*4 + w;
  const float4* wr = (const float4*)(wo + (size_t)i*512);
  const float4* bvv = (const float4*)bv;
  float a = 0.f;
  #pragma unroll
  for (int k=0;k<2;++k){
    float4 x = wr[lane*2+k];
    float4 y = bvv[lane*2+k];
    a += x.x*y.x + x.y*y.y + x.z*y.z + x.w*y.w;
  }
  #pragma unroll
  for (int dl=1; dl<64; dl<<=1) a += __shfl_xor(a, dl);
  if (lane==0) p[i] = a + bo[i];
}

// bc[v] = out_b[v] + out_w[v,:512].pc + out_w[v,512:].pt; one wave per row (grid 64)
__global__ __launch_bounds__(256) void k_bc2(const float* __restrict__ out_w,
    const float* __restrict__ pc, const float* __restrict__ pt,
    const float* __restrict__ out_b, float* __restrict__ bc){
  int w = threadIdx.x>>6, lane = threadIdx.x&63;
  int v = blockIdx.x*4 + w;
  const float4* wr = (const float4*)(out_w + (size_t)v*1024);
  float a = 0.f;
  #pragma unroll
  for (int k=0;k<4;++k){
    float4 x = wr[lane*4+k];
    int base = (lane*4+k)*4;                 // multiple of 4; never crosses 512 within a float4
    const float* pv = (base < 512) ? (pc + base) : (pt + (base-512));
    a += x.x*pv[0] + x.y*pv[1] + x.z*pv[2] + x.w*pv[3];
  }
  #pragma unroll
  for (int dl=1; dl<64; dl<<=1) a += __shfl_xor(a, dl);
  if (lane==0) bc[v] = a + out_b[v];
}

// ---- small MFMA prep GEMM ----
template<bool TA, int OMODE>
__global__ __launch_bounds__(256) void k_pgemm(const float* __restrict__ A, int lda,
    const float* __restrict__ B, int ldb, void* C1, void* C2, int ldc, int K){
  __shared__ us As[64][40];
  __shared__ us Bs[64][40];
  int tid=threadIdx.x, w=tid>>6, lane=tid&63, qd=lane>>4, ln=lane&15;
  int m0 = blockIdx.x*64, n0 = blockIdx.y*64;
  f32x4 acc[4] = {};
  for (int kc=0; kc<K/32; ++kc){
    int k0 = kc*32;
    if (!TA){
      int r=tid>>2, c=(tid&3)*8;
      const float* ap = A + (size_t)(m0+r)*lda + k0 + c;
      float4 f0=*(const float4*)ap, f1=*(const float4*)(ap+4);
      uint4 pk;
      pk.x=(u32)f2bf(f0.x)|((u32)f2bf(f0.y)<<16);
      pk.y=(u32)f2bf(f0.z)|((u32)f2bf(f0.w)<<16);
      pk.z=(u32)f2bf(f1.x)|((u32)f2bf(f1.y)<<16);
      pk.w=(u32)f2bf(f1.z)|((u32)f2bf(f1.w)<<16);
      *(uint4*)&As[r][c] = pk;
    } else {
      int kk=tid>>3, mp=(tid&7)*8;
      const float* ap = A + (size_t)(k0+kk)*lda + m0 + mp;
      #pragma unroll
      for (int i=0;i<8;++i) As[mp+i][kk] = f2bf(ap[i]);
    }
    { int kk=tid>>3, np=(tid&7)*8;
      const float* bp = B + (size_t)(k0+kk)*ldb + n0 + np;
      #pragma unroll
      for (int i=0;i<8;++i) Bs[np+i][kk] = f2bf(bp[i]);
    }
    __syncthreads();
    bf16x8 a = *(const bf16x8*)&As[16*w+ln][qd*8];
    #pragma unroll
    for (int j=0;j<4;++j){
      bf16x8 bb = *(const bf16x8*)&Bs[16*j+ln][qd*8];
      acc[j] = MFMA(a, bb, acc[j]);
    }
    __syncthreads();
  }
  #pragma unroll
  for (int j=0;j<4;++j){
    #pragma unroll
    for (int r=0;r<4;++r){
      size_t idx = (size_t)(m0+16*w+qd*4+r)*ldc + (n0+16*j+ln);
      float v = acc[j][r];
      if (OMODE==0) ((float*)C1)[idx] = v;
      else if (OMODE==1) ((us*)C1)[idx] = f2bf(v);
      else {
        us h = f2bf(v);
        ((us*)C1)[idx] = h;
        ((us*)C2)[idx] = f2bf(v - bf2f(h));
      }
    }
  }
}

// ---------------- persistent LSTM v6 (L2-local h exchange, builtin-only) ----
// 256 blocks = 32 e-slices x 8 b-tiles. W slice in LDS, c-state in registers.
// Flags: agent-scope relaxed atomics (r6-proven) in BOTH paths.
// h exchange: if the 32 blocks of this b-group verifiably share one XCD
// (s_getreg XCC_ID, m09-verified), h stores/loads are PLAIN ops through the
// shared XCD L2 (~200cy) instead of agent-scope L3 (~900cy). Safe because hs
// addresses are t-fresh: a reader's L1 never held an hs line before its one
// read (own stores are write-through no-allocate). Fallback: exact r6 path.
__global__ __launch_bounds__(256, 1) void k_lstm_all(
    const us* __restrict__ h0, const us* __restrict__ xbf,
    const us* __restrict__ Wp, const float* __restrict__ biasc,
    const float* __restrict__ c0, us* __restrict__ hs,
    unsigned* __restrict__ bars){
  extern __shared__ us Wf[];  // [24][4][64][8] us = 98304 B
  int tid = threadIdx.x, w = tid>>6, lane = tid&63, qd = lane>>4, ln = lane&15;
  int bb = blockIdx.x & 7, eb = blockIdx.x >> 3;
  int b0 = bb*64, e0 = eb*16;

  // publish this block's XCC id (once, agent scope)
  u32 myxcc = 0;
  asm volatile("s_getreg_b32 %0, hwreg(HW_REG_XCC_ID)" : "=s"(myxcc));
  unsigned* xcds = bars + 4096 + (size_t)bb*512;   // u32 units; 64B-stride slots
  if (tid == 0)
    __hip_atomic_store(xcds + eb*16, myxcc + 1u, __ATOMIC_RELAXED, __HIP_MEMORY_SCOPE_AGENT);

  // load W slice (98 KB) once, coalesced
  {
    const uint4* src = (const uint4*)(Wp + (size_t)eb*49152);
    uint4* dst = (uint4*)Wf;
    #pragma unroll
    for (int i=0;i<24;++i) dst[tid + 256*i] = src[tid + 256*i];
  }
  int bA = b0 + 16*w + ln;      // row for A-fragment loads
  int bC = b0 + 16*w + qd*4;    // rows for cell update (+r)
  int e  = e0 + ln;
  float bias_[4], c_[4];
  #pragma unroll
  for (int j=0;j<4;++j) bias_[j] = biasc[j*512 + e];
  #pragma unroll
  for (int r=0;r<4;++r) c_[r] = c0[(size_t)(bC+r)*512 + e];
  __syncthreads();

  // one-time: gather the group's 32 XCC ids, decide fast (XCD-uniform) path
  bool fast;
  {
    const unsigned* xp = xcds + (lane&31)*16;
    u32 ids;
    while (true){
      ids = __hip_atomic_load(xp, __ATOMIC_RELAXED, __HIP_MEMORY_SCOPE_AGENT);
      if (__all((int)(ids != 0))) break;
      __builtin_amdgcn_s_sleep(8);
    }
    u32 id0 = (u32)__shfl((int)ids, 0);
    fast = __all((int)(ids == id0));
  }

  unsigned* flags = bars + (size_t)bb*512;   // 2KB per group; flag eb at 64B stride
  unsigned* myflag = flags + eb*16;
  const unsigned* pollp = flags + (lane&31)*16;
  f32x4 xacc[4] = {};             // x-part of gates for current step (x_0 = 0)
  for (int t=0; t<64; ++t){
    if (t > 0){
      unsigned tgt = (unsigned)t;
      while (true){
        unsigned v = __hip_atomic_load(pollp, __ATOMIC_RELAXED, __HIP_MEMORY_SCOPE_AGENT);
        if (__all((int)(v >= tgt))) break;
        __builtin_amdgcn_s_sleep(1);
      }
      asm volatile("" ::: "memory");   // no hoisting of h loads above the poll
    }
    bf16x8 afr[16];
    if (t == 0){
      const us* hrow = h0 + (size_t)bA*512;   // prep output: cached loads fine
      #pragma unroll
      for (int kc=0; kc<16; ++kc)
        afr[kc] = *(const bf16x8*)(hrow + kc*32 + qd*8);
    } else if (fast){
      // plain 16B loads: L1-cold by address freshness, served by shared XCD L2
      const us* hrow = hs + ((size_t)bA*64 + (t-1))*512;
      #pragma unroll
      for (int kc=0; kc<16; ++kc)
        afr[kc] = *(const bf16x8*)(hrow + kc*32 + qd*8);
    } else {
      const u64* hq = (const u64*)(hs + ((size_t)bA*64 + (t-1))*512);
      u64 q0[16], q1[16];
      #pragma unroll
      for (int kc=0; kc<16; ++kc){
        q0[kc] = __hip_atomic_load(hq + kc*8 + qd*2 + 0, __ATOMIC_RELAXED, __HIP_MEMORY_SCOPE_AGENT);
        q1[kc] = __hip_atomic_load(hq + kc*8 + qd*2 + 1, __ATOMIC_RELAXED, __HIP_MEMORY_SCOPE_AGENT);
      }
      #pragma unroll
      for (int kc=0; kc<16; ++kc){
        union { u64 q[2]; bf16x8 v; } u_;
        u_.q[0] = q0[kc]; u_.q[1] = q1[kc];
        afr[kc] = u_.v;
      }
    }
    f32x4 acc[4] = {xacc[0], xacc[1], xacc[2], xacc[3]};
    #pragma unroll
    for (int kc=0; kc<16; ++kc){
      #pragma unroll
      for (int j=0;j<4;++j){
        bf16x8 bfrag = *(const bf16x8*)&Wf[(size_t)((kc*4+j)*64 + lane)*8];
        acc[j] = MFMA(afr[kc], bfrag, acc[j]);
      }
    }
    // cell update: lane holds i,f,g,o for (b = bC+r, e)
    us hb[4];
    #pragma unroll
    for (int r=0;r<4;++r){
      float iv = acc[0][r]+bias_[0], fv = acc[1][r]+bias_[1];
      float gv = acc[2][r]+bias_[2], ov = acc[3][r]+bias_[3];
      float cc2 = sigf(fv)*c_[r] + sigf(iv)*tanh_(gv);
      c_[r] = cc2;
      hb[r] = f2bf(sigf(ov)*tanh_(cc2));
    }
    // pack 4 lanes' bf16 into 8B and store h
    #pragma unroll
    for (int r=0;r<4;++r){
      u32 v = hb[r];
      u32 p = v | (((u32)__shfl_xor((int)v, 1)) << 16);
      u64 q = (u64)p | (((u64)(u32)__shfl_xor((int)p, 2)) << 32);
      if ((lane & 3) == 0){
        size_t idx = ((size_t)(bC+r)*64 + t)*512 + e0 + ln;   // ln multiple of 4 here
        if (fast)
          *(u64*)(hs + idx) = q;    // write-through to shared XCD L2
        else
          __hip_atomic_store((u64*)(hs + idx), q, __ATOMIC_RELAXED, __HIP_MEMORY_SCOPE_AGENT);
      }
    }
    if (t < 63){
      __syncthreads();   // drains vmcnt(0): h stores acked (L2 fast / L3 slow)
      if (tid == 0)
        __hip_atomic_store(myflag, (unsigned)(t+1), __ATOMIC_RELAXED, __HIP_MEMORY_SCOPE_AGENT);
      // overlap: x-part of gates for step t+1 (independent of h_t)
      const us* xrow = xbf + ((size_t)(t+1)*512 + bA)*256;
      f32x4 xa[4] = {};
      #pragma unroll
      for (int kx=0; kx<8; ++kx){
        bf16x8 xf = *(const bf16x8*)(xrow + kx*32 + qd*8);
        #pragma unroll
        for (int j=0;j<4;++j){
          bf16x8 bfrag = *(const bf16x8*)&Wf[(size_t)(((16+kx)*4+j)*64 + lane)*8];
          xa[j] = MFMA(xf, bfrag, xa[j]);
        }
      }
      #pragma unroll
      for (int j=0;j<4;++j) xacc[j] = xa[j];
    }
  }
}

// ------- C = bf16(alpha*(A @ W^T + bias)), A bf16 (M x 512), W bf16 (N x 512) -------
__global__ __launch_bounds__(256) void k_gemm(
    const us* __restrict__ Ap, const us* __restrict__ W,
    const float* __restrict__ bias, float alpha, us* __restrict__ C){
  __shared__ us As[128][40];
  __shared__ us Ws[128][40];
  int tid = threadIdx.x; int w = tid>>6; int lane=tid&63;
  int qd=lane>>4, ln=lane&15;
  int m0 = blockIdx.x*128, n0 = blockIdx.y*128;
  int wm = (w&1)*64, wn=(w>>1)*64;
  f32x4 acc[4][4] = {};
  int row = tid>>1; int cp = (tid&1)*16;
  for (int kc=0;kc<16;++kc){
    int k0=kc*32;
    { const uint4* ap = (const uint4*)(Ap + (size_t)(m0+row)*512 + k0+cp);
      *(uint4*)&As[row][cp]=ap[0]; *(uint4*)&As[row][cp+8]=ap[1];
    }
    { const uint4* wp = (const uint4*)(W + (size_t)(n0+row)*512 + k0+cp);
      *(uint4*)&Ws[row][cp]=wp[0]; *(uint4*)&Ws[row][cp+8]=wp[1];
    }
    __syncthreads();
    bf16x8 af[4], bfr[4];
    #pragma unroll
    for (int i=0;i<4;++i) af[i]  = *(const bf16x8*)&As[wm+16*i+ln][qd*8];
    #pragma unroll
    for (int j=0;j<4;++j) bfr[j] = *(const bf16x8*)&Ws[wn+16*j+ln][qd*8];
    #pragma unroll
    for (int i=0;i<4;++i)
      #pragma unroll
      for (int j=0;j<4;++j) acc[i][j]=MFMA(af[i],bfr[j],acc[i][j]);
    __syncthreads();
  }
  #pragma unroll
  for (int j=0;j<4;++j){
    int col = n0+wn+16*j+ln;
    float bv = bias[col];
    #pragma unroll
    for (int i=0;i<4;++i){
      #pragma unroll
      for (int r=0;r<4;++r){
        int rm = m0+wm+16*i+qd*4+r;
        C[(size_t)rm*512 + col] = f2bf(alpha*(acc[i][j][r]+bv));
      }
    }
  }
}

// ---------------- fused attention + output projection (v3) ----------------
template<int S>
struct alignas(16) ASmem3 {
  static constexpr int SP  = (S<32)?32:S;
  static constexpr int SPp = SP+8;
  us Pbh[64][SPp];
  us Pbl[64][SPp];
  union {
    us Es[S][72];
    struct { us Eh[64][72]; us El[64][72]; } t;
  } u;
  us Ph[64][72];
  us Pl[64][72];
};

template<int S, bool ACC>
__global__ __launch_bounds__(256) void k_attn3(const us* __restrict__ hGp,
    const float* __restrict__ enc, const us* __restrict__ Mvh,
    const us* __restrict__ Mvl, float* __restrict__ out){
  constexpr int NJ  = S/16;
  constexpr int KC2 = ((S<32)?32:S)/32;
  extern __shared__ char smraw[];
  ASmem3<S>& sm = *reinterpret_cast<ASmem3<S>*>(smraw);
  int b = blockIdx.x;
  int tid=threadIdx.x, w=tid>>6, lane=tid&63, qd=lane>>4, ln=lane&15;

  // ---- phase 1: S = hG @ enc^T ----
  f32x4 sacc[NJ];
  #pragma unroll
  for (int j=0;j<NJ;++j) sacc[j] = (f32x4){0.f,0.f,0.f,0.f};
  const us* hrow = hGp + ((size_t)(b*64 + 16*w + ln))*512;
  for (int ec=0; ec<8; ++ec){
    int e0 = ec*64;
    { int s = tid>>2, ep=(tid&3)*16;
      if (S==64 || tid < 4*S){
        const float* ap = enc + ((size_t)b*S + s)*512 + e0 + ep;
        float4 f0=*(const float4*)ap, f1=*(const float4*)(ap+4);
        float4 f2=*(const float4*)(ap+8), f3=*(const float4*)(ap+12);
        float fv[16]={f0.x,f0.y,f0.z,f0.w,f1.x,f1.y,f1.z,f1.w,
                      f2.x,f2.y,f2.z,f2.w,f3.x,f3.y,f3.z,f3.w};
        u32 pk[8];
        #pragma unroll
        for (int i=0;i<8;++i)
          pk[i] = (u32)f2bf(fv[2*i]) | ((u32)f2bf(fv[2*i+1])<<16);
        uint4* d = (uint4*)&sm.u.Es[s][ep];
        d[0] = make_uint4(pk[0],pk[1],pk[2],pk[3]);
        d[1] = make_uint4(pk[4],pk[5],pk[6],pk[7]);
      }
    }
    __syncthreads();
    #pragma unroll
    for (int kcl=0;kcl<2;++kcl){
      bf16x8 a = *(const bf16x8*)(hrow + e0 + kcl*32 + qd*8);
      #pragma unroll
      for (int j=0;j<NJ;++j){
        bf16x8 bb = *(const bf16x8*)&sm.u.Es[16*j+ln][kcl*32+qd*8];
        sacc[j] = MFMA(a, bb, sacc[j]);
      }
    }
    __syncthreads();
  }

  // ---- softmax, fully in-register ----
  #pragma unroll
  for (int r=0;r<4;++r){
    float m = sacc[0][r];
    #pragma unroll
    for (int j=1;j<NJ;++j) m = fmaxf(m, sacc[j][r]);
    #pragma unroll
    for (int dl=1; dl<16; dl<<=1) m = fmaxf(m, __shfl_xor(m, dl));
    float ssum = 0.f;
    #pragma unroll
    for (int j=0;j<NJ;++j){ float e_=__expf(sacc[j][r]-m); sacc[j][r]=e_; ssum+=e_; }
    #pragma unroll
    for (int dl=1; dl<16; dl<<=1) ssum += __shfl_xor(ssum, dl);
    float inv = 1.0f/ssum;
    int R = 16*w + qd*4 + r;
    #pragma unroll
    for (int j=0;j<NJ;++j){
      float pv = sacc[j][r]*inv;
      us h = f2bf(pv);
      sm.Pbh[R][16*j+ln] = h;
      sm.Pbl[R][16*j+ln] = f2bf(pv - bf2f(h));
    }
    if (S==16){ sm.Pbh[R][16+ln]=0; sm.Pbl[R][16+ln]=0; }
  }

  // ---- phase 2 ----
  f32x4 Lacc[4][4] = {};
  for (int ec=0; ec<8; ++ec){
    int e0 = ec*64;
    { int s = tid>>2, ep=(tid&3)*16;
      if (S==64 || tid < 4*S){
        const float* ap = enc + ((size_t)b*S + s)*512 + e0 + ep;
        float4 f0=*(const float4*)ap, f1=*(const float4*)(ap+4);
        float4 f2=*(const float4*)(ap+8), f3=*(const float4*)(ap+12);
        float fv[16]={f0.x,f0.y,f0.z,f0.w,f1.x,f1.y,f1.z,f1.w,
                      f2.x,f2.y,f2.z,f2.w,f3.x,f3.y,f3.z,f3.w};
        #pragma unroll
        for (int i=0;i<16;++i){
          float v = fv[i]; us h = f2bf(v);
          sm.u.t.Eh[ep+i][s] = h;
          sm.u.t.El[ep+i][s] = f2bf(v - bf2f(h));
        }
      } else if (S==16 && tid < 128){
        int s2 = 16 + ((tid-64)>>2);
        #pragma unroll
        for (int i=0;i<16;++i){ sm.u.t.Eh[ep+i][s2]=0; sm.u.t.El[ep+i][s2]=0; }
      }
    }
    __syncthreads();
    f32x4 pacc[4] = {};
    #pragma unroll
    for (int kcl=0;kcl<KC2;++kcl){
      bf16x8 ah = *(const bf16x8*)&sm.Pbh[16*w+ln][kcl*32+qd*8];
      bf16x8 al = *(const bf16x8*)&sm.Pbl[16*w+ln][kcl*32+qd*8];
      #pragma unroll
      for (int j=0;j<4;++j){
        bf16x8 bh = *(const bf16x8*)&sm.u.t.Eh[16*j+ln][kcl*32+qd*8];
        bf16x8 bl = *(const bf16x8*)&sm.u.t.El[16*j+ln][kcl*32+qd*8];
        pacc[j] = MFMA(ah, bh, pacc[j]);
        pacc[j] = MFMA(ah, bl, pacc[j]);
        pacc[j] = MFMA(al, bh, pacc[j]);
      }
    }
    #pragma unroll
    for (int j=0;j<4;++j)
      #pragma unroll
      for (int r=0;r<4;++r){
        float v = pacc[j][r]; us h = f2bf(v);
        sm.Ph[16*w+qd*4+r][16*j+ln] = h;
        sm.Pl[16*w+qd*4+r][16*j+ln] = f2bf(v - bf2f(h));
      }
    __syncthreads();
    #pragma unroll
    for (int kcl=0;kcl<2;++kcl){
      bf16x8 ah[4], al[4];
      #pragma unroll
      for (int i=0;i<4;++i){
        ah[i] = *(const bf16x8*)&sm.Ph[16*i+ln][kcl*32+qd*8];
        al[i] = *(const bf16x8*)&sm.Pl[16*i+ln][kcl*32+qd*8];
      }
      #pragma unroll
      for (int j=0;j<4;++j){
        int v = 64*w + 16*j + ln;
        bf16x8 mh = *(const bf16x8*)(Mvh + (size_t)v*512 + e0 + kcl*32 + qd*8);
        bf16x8 ml = *(const bf16x8*)(Mvl + (size_t)v*512 + e0 + kcl*32 + qd*8);
        #pragma unroll
        for (int i=0;i<4;++i){
          Lacc[i][j] = MFMA(ah[i], mh, Lacc[i][j]);
          Lacc[i][j] = MFMA(ah[i], ml, Lacc[i][j]);
          Lacc[i][j] = MFMA(al[i], mh, Lacc[i][j]);
        }
      }
    }
  }
  // epilogue
  #pragma unroll
  for (int i=0;i<4;++i){
    #pragma unroll
    for (int j=0;j<4;++j){
      int v = 64*w + 16*j + ln;
      #pragma unroll
      for (int r=0;r<4;++r){
        size_t addr = ((size_t)b*64 + 16*i + qd*4 + r)*256 + v;
        if (ACC) out[addr] += Lacc[i][j][r];
        else     out[addr]  = Lacc[i][j][r];
      }
    }
  }
}

// ---------------- entmax-1.5 in place over rows of 256 ----------------
__global__ __launch_bounds__(256) void k_entmax(float* __restrict__ out,
                                                const float* __restrict__ bc){
  int tid=threadIdx.x; int w=tid>>6; int lane=tid&63;
  float4 bcv = *(const float4*)(bc + lane*4);
  int base = blockIdx.x*16 + w*4;
  for (int i=0;i<4;++i){
    int row = base + i;
    float* rp = out + (size_t)row*256 + lane*4;
    float4 d = *(const float4*)rp;
    float z[4] = {0.5f*(d.x+bcv.x), 0.5f*(d.y+bcv.y), 0.5f*(d.z+bcv.z), 0.5f*(d.w+bcv.w)};
    float m = fmaxf(fmaxf(z[0],z[1]), fmaxf(z[2],z[3]));
    #pragma unroll
    for (int dl=1; dl<64; dl<<=1) m = fmaxf(m, __shfl_xor(m, dl));
    #pragma unroll
    for (int k=0;k<4;++k) z[k] -= m;
    float tau = -1.0f;
    for (int it=0; it<14; ++it){
      float s1=0.f, s2=0.f;
      #pragma unroll
      for (int k=0;k<4;++k){
        float dd = z[k]-tau; dd = fmaxf(dd, 0.f);
        s1 += dd; s2 += dd*dd;
      }
      #pragma unroll
      for (int dl=1; dl<64; dl<<=1){ s1 += __shfl_xor(s1, dl); s2 += __shfl_xor(s2, dl); }
      tau += (s2 - 1.0f) / (2.0f*fmaxf(s1, 1e-12f));
    }
    float4 y;
    { float dd;
      dd = fmaxf(z[0]-tau,0.f); y.x = dd*dd;
      dd = fmaxf(z[1]-tau,0.f); y.y = dd*dd;
      dd = fmaxf(z[2]-tau,0.f); y.z = dd*dd;
      dd = fmaxf(z[3]-tau,0.f); y.w = dd*dd;
    }
    *(float4*)rp = y;
  }
}

// ---------------- launch ----------------

extern "C" void kernel_launch(void* const* d_in, const int* in_sizes, int n_in,
                              void* d_out, int out_size, void* d_ws, size_t ws_size,
                              hipStream_t stream){
  (void)in_sizes; (void)n_in; (void)out_size; (void)ws_size;
  const float* char_enc = (const float*)d_in[0];
  const float* char_hn0 = (const float*)d_in[1];
  const float* char_cn0 = (const float*)d_in[2];
  const float* tag_enc  = (const float*)d_in[3];
  const float* tag_hn0  = (const float*)d_in[4];
  const float* tag_cn0  = (const float*)d_in[5];
  const float* true_out = (const float*)d_in[6];
  const float* w_ih = (const float*)d_in[7];
  const float* w_hh = (const float*)d_in[8];
  const float* b_ih = (const float*)d_in[9];
  const float* b_hh = (const float*)d_in[10];
  const float* c_wq = (const float*)d_in[11];
  const float* c_wk = (const float*)d_in[12];
  const float* c_wv = (const float*)d_in[13];
  const float* c_bq = (const float*)d_in[14];
  const float* c_bv = (const float*)d_in[16];
  const float* c_wo = (const float*)d_in[17];
  const float* c_bo = (const float*)d_in[18];
  const float* t_wq = (const float*)d_in[19];
  const float* t_wk = (const float*)d_in[20];
  const float* t_wv = (const float*)d_in[21];
  const float* t_bq = (const float*)d_in[22];
  const float* t_bv = (const float*)d_in[24];
  const float* t_wo = (const float*)d_in[25];
  const float* t_bo = (const float*)d_in[26];
  const float* out_w = (const float*)d_in[27];
  const float* out_b = (const float*)d_in[28];
  float* out = (float*)d_out;

  char* base = (char*)d_ws;
  // region A: prep/LSTM scratch, later overwritten by hG
  char* regA = base;
  us*    Wp    = (us*)   (regA + 0);          // 3,145,728 (fragment-linear Wc)
  float* biasc = (float*)(regA + 3145728);    // 8,192
  us*    h0    = (us*)   (regA + 3153920);    // 524,288
  float* cst   = (float*)(regA + 3678208);    // 1,048,576
  float* M1f   = (float*)(regA + 4726784);    // 524,288
  float* M2f   = (float*)(regA + 5251072);    // 524,288
  us*    xbf   = (us*)   (regA + 5775360);    // 16,777,216
  us*    hG    = (us*)   regA;                // 33,554,432 (after LSTM)
  // region B: survivors
  char* regB = base + 33554432;
  us*    Gc_w  = (us*)(regB + 0);             // 524,288
  us*    Gt_w  = (us*)(regB + 524288);        // 524,288
  us*    M1vh  = (us*)(regB + 1048576);       // 262,144
  us*    M1vl  = (us*)(regB + 1310720);       // 262,144
  us*    M2vh  = (us*)(regB + 1572864);       // 262,144
  us*    M2vl  = (us*)(regB + 1835008);       // 262,144
  float* u_c   = (float*)(regB + 2097152);    // 2,048
  float* u_t   = (float*)(regB + 2099200);    // 2,048
  float* p_c   = (float*)(regB + 2101248);    // 2,048
  float* p_t   = (float*)(regB + 2103296);    // 2,048
  float* bc    = (float*)(regB + 2105344);    // 1,024
  // region C: hs (b, t, e) bf16
  us*    hs    = (us*)(base + 33554432 + 2106368);  // 33,554,432
  unsigned* bars = (unsigned*)(base + 33554432 + 2106368 + 33554432); // 32,768 (flags 16K + xcc 16K)

  static bool attr_done = false;
  if (!attr_done){
    hipFuncSetAttribute(reinterpret_cast<const void*>(&k_lstm_all),
                        hipFuncAttributeMaxDynamicSharedMemorySize, 131072);
    attr_done = true;
  }

  // ---- prep ----
  hipMemsetAsync(bars, 0, 32768, stream);
  hipMemsetAsync(u_c, 0, 4096, stream);   // u_c + u_t (atomicAdd targets)
  k_prep_wperm<<<2048, 768, 0, stream>>>(w_hh, w_ih, b_ih, b_hh, Wp, biasc);
  k_prep_state<<<1024, 256, 0, stream>>>(char_hn0, tag_hn0, char_cn0, tag_cn0, h0, cst);
  k_xprep<<<4096, 256, 0, stream>>>(true_out, xbf);
  k_pgemm<true,1><<<dim3(8,8),256,0,stream>>>(c_wk, 512, c_wq, 512, Gc_w, nullptr, 512, 512);
  k_pgemm<true,1><<<dim3(8,8),256,0,stream>>>(t_wk, 512, t_wq, 512, Gt_w, nullptr, 512, 512);
  k_pgemm<false,0><<<dim3(4,8),256,0,stream>>>(out_w,     1024, c_wo, 512, M1f, nullptr, 512, 512);
  k_pgemm<false,0><<<dim3(4,8),256,0,stream>>>(out_w+512, 1024, t_wo, 512, M2f, nullptr, 512, 512);
  k_pgemm<false,2><<<dim3(4,8),256,0,stream>>>(M1f, 512, c_wv, 512, M1vh, M1vl, 512, 512);
  k_pgemm<false,2><<<dim3(4,8),256,0,stream>>>(M2f, 512, t_wv, 512, M2vh, M2vl, 512, 512);
  k_uvec2<<<dim3(2,8),256,0,stream>>>(c_bq, c_wk, u_c);
  k_uvec2<<<dim3(2,8),256,0,stream>>>(t_bq, t_wk, u_t);
  k_pvec2<<<128,256,0,stream>>>(c_wo, c_bv, c_bo, p_c);
  k_pvec2<<<128,256,0,stream>>>(t_wo, t_bv, t_bo, p_t);
  k_bc2<<<64,256,0,stream>>>(out_w, p_c, p_t, out_b, bc);

  // ---- LSTM: single persistent dispatch, 64 steps ----
  k_lstm_all<<<256, 256, 98304, stream>>>(h0, xbf, Wp, biasc, cst, hs, bars);

  const float scale = 0.044194173824159216f;  // 1/sqrt(512)
  // ---- char attention ----
  k_gemm<<<dim3(256,4),256,0,stream>>>(hs, Gc_w, u_c, scale, hG);
  k_attn3<64,false><<<512,256,sizeof(ASmem3<64>),stream>>>(hG, char_enc, M1vh, M1vl, out);
  // ---- tag attention ----
  k_gemm<<<dim3(256,4),256,0,stream>>>(hs, Gt_w, u_t, scale, hG);
  k_attn3<16,true ><<<512,256,sizeof(ASmem3<16>),stream>>>(hG, tag_enc, M2vh, M2vl, out);
  // ---- entmax-1.5 ----
  k_entmax<<<2048,256,0,stream>>>(out, bc);
}